// Round 4
// baseline (7313.894 us; speedup 1.0000x reference)
//
#include <hip/hip_runtime.h>
#include <hip/hip_bf16.h>

typedef unsigned int  u32;
typedef unsigned short u16;
typedef unsigned long long u64;
typedef float f32x4 __attribute__((ext_vector_type(4)));
typedef short bf16x8 __attribute__((ext_vector_type(8)));
typedef u32 u32x4 __attribute__((ext_vector_type(4)));

#define AGENT __HIP_MEMORY_SCOPE_AGENT
__device__ inline float aloadf(const float* p){ return __hip_atomic_load(p, __ATOMIC_RELAXED, AGENT); }
__device__ inline void  astoref(float* p, float v){ __hip_atomic_store(p, v, __ATOMIC_RELAXED, AGENT); }
__device__ inline int   aloadi(const int* p){ return __hip_atomic_load(p, __ATOMIC_RELAXED, AGENT); }
__device__ inline void  astorei_rel(int* p, int v){ __hip_atomic_store(p, v, __ATOMIC_RELEASE, AGENT); }
__device__ inline u64   aload64(const u64* p){ return __hip_atomic_load(p, __ATOMIC_RELAXED, AGENT); }
__device__ inline void  astore64(u64* p, u64 v){ __hip_atomic_store(p, v, __ATOMIC_RELAXED, AGENT); }
__device__ inline void  astore32(u32* p, u32 v){ __hip_atomic_store(p, v, __ATOMIC_RELAXED, AGENT); }
__device__ inline u64   tagpack(u32 tag, float v){ return ((u64)tag << 32) | (u64)__float_as_uint(v); }

__device__ __host__ inline u16 f2bf(float f){
  u32 u = __builtin_bit_cast(u32, f);
  u += 0x7fffu + ((u >> 16) & 1u);
  return (u16)(u >> 16);
}
__device__ inline float bflo(u32 a){ return __uint_as_float(a << 16); }
__device__ inline float bfhi(u32 a){ return __uint_as_float(a & 0xffff0000u); }
__device__ inline float sigm(float x){ return 1.f/(1.f + expf(-x)); }

__device__ inline float wred_sum(float v){
#pragma unroll
  for (int m = 32; m >= 1; m >>= 1) v += __shfl_xor(v, m, 64);
  return v;
}
__device__ inline float bred_sum(float v, float* red, int tid){
  v = wred_sum(v);
  if ((tid & 63) == 0) red[tid >> 6] = v;
  __syncthreads();
  float r = red[0] + red[1] + red[2] + red[3];
  __syncthreads();
  return r;
}
__device__ inline float bred_max(float v, float* red, int tid){
#pragma unroll
  for (int m = 32; m >= 1; m >>= 1) v = fmaxf(v, __shfl_xor(v, m, 64));
  if ((tid & 63) == 0) red[tid >> 6] = v;
  __syncthreads();
  float r = fmaxf(fmaxf(red[0], red[1]), fmaxf(red[2], red[3]));
  __syncthreads();
  return r;
}

// 1024-dot, 4-elem chunks (LDS reads 2-way-aliased = free). Per-lane partial.
__device__ inline float dot1024(const u16* __restrict__ row, const float* h, int lane){
  float s = 0.f;
#pragma unroll
  for (int c = 0; c < 4; ++c){
    int e = 4 * lane + 256 * c;
    uint2 a = *(const uint2*)(row + e);
    float4 x = *(const float4*)(h + e);
    s = fmaf(bflo(a.x), x.x, s); s = fmaf(bfhi(a.x), x.y, s);
    s = fmaf(bflo(a.y), x.z, s); s = fmaf(bfhi(a.y), x.w, s);
  }
  return s;
}

// 4-row batched GEMV, h LDS reads amortized, 4 independent chains, reduced.
__device__ inline float4 dot4(const u16* __restrict__ W, size_t r, size_t rs,
                              const float* h, int lane){
  const u16* p0 = W + (r         ) * 1024;
  const u16* p1 = W + (r + rs    ) * 1024;
  const u16* p2 = W + (r + 2 * rs) * 1024;
  const u16* p3 = W + (r + 3 * rs) * 1024;
  float s0 = 0, s1 = 0, s2 = 0, s3 = 0;
#pragma unroll
  for (int c = 0; c < 4; ++c){
    int e = 4 * lane + 256 * c;
    float4 x = *(const float4*)(h + e);
    uint2 a0 = *(const uint2*)(p0 + e);
    uint2 a1 = *(const uint2*)(p1 + e);
    uint2 a2 = *(const uint2*)(p2 + e);
    uint2 a3 = *(const uint2*)(p3 + e);
    s0 = fmaf(bflo(a0.x), x.x, s0); s0 = fmaf(bfhi(a0.x), x.y, s0);
    s0 = fmaf(bflo(a0.y), x.z, s0); s0 = fmaf(bfhi(a0.y), x.w, s0);
    s1 = fmaf(bflo(a1.x), x.x, s1); s1 = fmaf(bfhi(a1.x), x.y, s1);
    s1 = fmaf(bflo(a1.y), x.z, s1); s1 = fmaf(bfhi(a1.y), x.w, s1);
    s2 = fmaf(bflo(a2.x), x.x, s2); s2 = fmaf(bfhi(a2.x), x.y, s2);
    s2 = fmaf(bflo(a2.y), x.z, s2); s2 = fmaf(bfhi(a2.y), x.w, s2);
    s3 = fmaf(bflo(a3.x), x.x, s3); s3 = fmaf(bfhi(a3.x), x.y, s3);
    s3 = fmaf(bflo(a3.y), x.z, s3); s3 = fmaf(bfhi(a3.y), x.w, s3);
  }
  s0 = wred_sum(s0); s1 = wred_sum(s1); s2 = wred_sum(s2); s3 = wred_sum(s3);
  return make_float4(s0, s1, s2, s3);
}

// ---------------------------------------------------------------- fp32 -> bf16
__global__ void k_cvt(const float* __restrict__ s, u16* __restrict__ d, int n4){
  int i = blockIdx.x * 256 + threadIdx.x;
  int stride = gridDim.x * 256;
  const float4* s4 = (const float4*)s;
  for (; i < n4; i += stride){
    float4 v = s4[i];
    ushort4 o;
    o.x = f2bf(v.x); o.y = f2bf(v.y); o.z = f2bf(v.z); o.w = f2bf(v.w);
    ((ushort4*)d)[i] = o;
  }
}

// ---------------------------------------------------------------- img xp GEMM
__global__ __launch_bounds__(256, 1) void k_gemm_xp(
    const u16* __restrict__ A,
    const u16* __restrict__ B0, const u16* __restrict__ B1,
    const float* __restrict__ bias0, const float* __restrict__ bias1,
    float* __restrict__ C0, float* __restrict__ C1)
{
  const int K = 2048, N = 2048;
  const int bx = blockIdx.x, by = blockIdx.y, z = blockIdx.z;
  const u16* B = z ? B1 : B0;
  const float* bias = z ? bias1 : bias0;
  float* C = z ? C1 : C0;
  const int tid = threadIdx.x;
  const int lane = tid & 63, wv = tid >> 6;
  const int m0 = by * 128, n0 = bx * 128;
  const int wm = (wv >> 1) * 64, wn = (wv & 1) * 64;

  __shared__ __align__(16) u16 lA[128 * 32];
  __shared__ __align__(16) u16 lB[128 * 32];

  f32x4 acc[4][4];
#pragma unroll
  for (int i = 0; i < 4; ++i)
#pragma unroll
    for (int j = 0; j < 4; ++j) acc[i][j] = (f32x4){0.f, 0.f, 0.f, 0.f};

  const int lrow = tid >> 2;
  const int lcol = (tid & 3) * 8;
  const u16* aBase = A + (size_t)(m0 + lrow) * K + lcol;
  const u16* bBase = B + (size_t)(n0 + lrow) * K + lcol;

  for (int kk = 0; kk < K; kk += 32){
#pragma unroll
    for (int io = 0; io < 2; ++io){
      __builtin_amdgcn_global_load_lds(
        (const __attribute__((address_space(1))) void*)(aBase + (size_t)io * 64 * K + kk),
        (__attribute__((address_space(3))) void*)((char*)lA + wv * 1024 + io * 4096), 16, 0, 0);
      __builtin_amdgcn_global_load_lds(
        (const __attribute__((address_space(1))) void*)(bBase + (size_t)io * 64 * K + kk),
        (__attribute__((address_space(3))) void*)((char*)lB + wv * 1024 + io * 4096), 16, 0, 0);
    }
    asm volatile("s_waitcnt vmcnt(0)");
    __syncthreads();

    bf16x8 af[4], bfr[4];
#pragma unroll
    for (int i = 0; i < 4; ++i){
      af[i]  = *(const bf16x8*)&lA[(wm + i * 16 + (lane & 15)) * 32 + (lane >> 4) * 8];
      bfr[i] = *(const bf16x8*)&lB[(wn + i * 16 + (lane & 15)) * 32 + (lane >> 4) * 8];
    }
#pragma unroll
    for (int i = 0; i < 4; ++i)
#pragma unroll
      for (int j = 0; j < 4; ++j)
        acc[i][j] = __builtin_amdgcn_mfma_f32_16x16x32_bf16(af[i], bfr[j], acc[i][j], 0, 0, 0);
    __syncthreads();
  }

  const int rbase = (lane >> 4) * 4;
  const int ccol = lane & 15;
#pragma unroll
  for (int i = 0; i < 4; ++i)
#pragma unroll
    for (int j = 0; j < 4; ++j){
      int col = n0 + wn + j * 16 + ccol;
      float bv = bias[col];
#pragma unroll
      for (int r2 = 0; r2 < 4; ++r2){
        int row = m0 + wm + i * 16 + rbase + r2;
        C[(size_t)row * N + col] = acc[i][j][r2] + bv;
      }
    }
}

// ---------------------------------------------------------------- q xp
__global__ __launch_bounds__(256, 1) void k_qxp(
    const float* __restrict__ qf,
    const float* __restrict__ W0, const float* __restrict__ W1,
    const float* __restrict__ bb0, const float* __restrict__ bb1,
    float* __restrict__ o0, float* __restrict__ o1)
{
  const int bx = blockIdx.x;
  const int z = blockIdx.y;
  const float* W = z ? W1 : W0;
  const float* bb = z ? bb1 : bb0;
  float* o = z ? o1 : o0;
  const int tid = threadIdx.x;
  __shared__ float xs[32 * 301];
  __shared__ float Ws[64 * 301];
  for (int idx = tid; idx < 32 * 300; idx += 256){
    int m = idx / 300, k = idx - m * 300;
    xs[m * 301 + k] = qf[idx];
  }
  for (int idx = tid; idx < 64 * 300; idx += 256){
    int j = idx / 300, k = idx - j * 300;
    Ws[j * 301 + k] = W[(size_t)(bx * 64 + j) * 300 + k];
  }
  __syncthreads();
  for (int i = 0; i < 8; ++i){
    int idx = tid + i * 256;
    int nl = idx >> 5, m = idx & 31;
    float s = 0;
    for (int k = 0; k < 300; ++k) s = fmaf(xs[m * 301 + k], Ws[nl * 301 + k], s);
    o[(size_t)m * 2048 + bx * 64 + nl] = s + bb[bx * 64 + nl];
  }
}

// ---------------------------------------------------------------- LSTM scans
// NO LDS. Weights in VGPRs (step-invariant). Each thread polls exactly the
// 16 tagged u64 words (32 h-values) it needs; h travels as bf16+tag16 in u32
// halves. No __syncthreads in the loop; waves self-synchronize via tags.
__global__ __launch_bounds__(256, 1) void k_scan(
    const float* __restrict__ WhA, const float* __restrict__ WhB,
    const float* __restrict__ WhC, const float* __restrict__ WhD,
    const float* __restrict__ xpA, const float* __restrict__ xpB,
    const float* __restrict__ xpC, const float* __restrict__ xpD,
    float* __restrict__ emb, float* __restrict__ embT,
    float* __restrict__ qemb, float* __restrict__ qembT,
    u32* hcomm /* [4][2][512] u32 = tag16<<16 | bf16 */)
{
  const int tid = threadIdx.x;
  const int dir = blockIdx.x >> 5;
  const int sub = blockIdx.x & 31;
  const float* Wh = dir == 0 ? WhA : dir == 1 ? WhB : dir == 2 ? WhC : WhD;
  const float* xp = dir == 0 ? xpA : dir == 1 ? xpB : dir == 2 ? xpC : xpD;
  const int L = (dir < 2) ? 1024 : 32;
  const int rev = dir & 1;
  float* oe  = (dir < 2) ? emb  : qemb;
  float* oeT = (dir < 2) ? embT : qembT;
  const int colbase = rev ? 512 : 0;
  const int eTL = (dir < 2) ? 1024 : 32;
  const int hbase = sub * 16;
  const int g = tid >> 4;        // h-element within block: e = hbase + g
  const int seg = tid & 15;      // k-chunk: k in {2*seg+32*i, +1}
  const bool pub = (seg == 0);

  int grows[4];
#pragma unroll
  for (int gate = 0; gate < 4; ++gate) grows[gate] = gate * 512 + hbase + g;

  // one-time: weights -> registers (packed bf16 pairs)
  u32 wpk0[16], wpk1[16], wpk2[16], wpk3[16];
  {
    const float2* r0 = (const float2*)(Wh + (size_t)grows[0] * 512) + seg;
    const float2* r1 = (const float2*)(Wh + (size_t)grows[1] * 512) + seg;
    const float2* r2 = (const float2*)(Wh + (size_t)grows[2] * 512) + seg;
    const float2* r3 = (const float2*)(Wh + (size_t)grows[3] * 512) + seg;
#pragma unroll
    for (int i = 0; i < 16; ++i){
      float2 a0 = r0[16 * i], a1 = r1[16 * i], a2 = r2[16 * i], a3 = r3[16 * i];
      wpk0[i] = (u32)f2bf(a0.x) | ((u32)f2bf(a0.y) << 16);
      wpk1[i] = (u32)f2bf(a1.x) | ((u32)f2bf(a1.y) << 16);
      wpk2[i] = (u32)f2bf(a2.x) | ((u32)f2bf(a2.y) << 16);
      wpk3[i] = (u32)f2bf(a3.x) | ((u32)f2bf(a3.y) << 16);
    }
  }

  float creg = 0.f;
  float xpv[4];
  if (pub){
    int t0 = rev ? (L - 1) : 0;
#pragma unroll
    for (int gate = 0; gate < 4; ++gate) xpv[gate] = xp[(size_t)t0 * 2048 + grows[gate]];
  }

  u32* hcd = hcomm + dir * 1024;  // [2][512]

  for (int t = 0; t < L; ++t){
    const u32 want = (u32)t;      // h_t carries tag t (t=0 from memset)
    const u64* hc64 = (const u64*)(hcd + (t & 1) * 512);
    u64 w[16];
#pragma unroll
    for (int i = 0; i < 16; ++i) w[i] = aload64(&hc64[seg + 16 * i]);
#pragma unroll
    for (int i = 0; i < 16; ++i){
      while (((u32)(w[i] >> 16) & 0xffffu) != want || (u32)(w[i] >> 48) != want)
        w[i] = aload64(&hc64[seg + 16 * i]);
    }
    float s0 = 0, s1 = 0, s2 = 0, s3 = 0;
#pragma unroll
    for (int i = 0; i < 16; ++i){
      float hx = bflo((u32)w[i]);          // tag bits shift out
      float hy = bflo((u32)(w[i] >> 32));
      s0 = fmaf(bflo(wpk0[i]), hx, s0); s0 = fmaf(bfhi(wpk0[i]), hy, s0);
      s1 = fmaf(bflo(wpk1[i]), hx, s1); s1 = fmaf(bfhi(wpk1[i]), hy, s1);
      s2 = fmaf(bflo(wpk2[i]), hx, s2); s2 = fmaf(bfhi(wpk2[i]), hy, s2);
      s3 = fmaf(bflo(wpk3[i]), hx, s3); s3 = fmaf(bfhi(wpk3[i]), hy, s3);
    }
#pragma unroll
    for (int m = 1; m < 16; m <<= 1){
      s0 += __shfl_xor(s0, m, 64); s1 += __shfl_xor(s1, m, 64);
      s2 += __shfl_xor(s2, m, 64); s3 += __shfl_xor(s3, m, 64);
    }
    if (pub){
      const int trow = rev ? (L - 1 - t) : t;
      float gi = s0 + xpv[0], gf = s1 + xpv[1], gg = s2 + xpv[2], go = s3 + xpv[3];
      creg = sigm(gf) * creg + sigm(gi) * tanhf(gg);
      float h = sigm(go) * tanhf(creg);
      astore32(&hcd[((t + 1) & 1) * 512 + hbase + g],
               ((u32)(t + 1) << 16) | (u32)f2bf(h));   // publish FIRST
      int col = colbase + hbase + g;
      oe[(size_t)trow * 1024 + col] = h;
      oeT[(size_t)col * eTL + trow] = h;
      if (t + 1 < L){
        int tn = rev ? (L - 2 - t) : (t + 1);
#pragma unroll
        for (int gate = 0; gate < 4; ++gate) xpv[gate] = xp[(size_t)tn * 2048 + grows[gate]];
      }
    }
  }
}

// ---------------------------------------------------------------- decoder
#define DG 256
__device__ inline void dbar(int* st, int b, int pc, int tid){
  __syncthreads();
  if (tid == 0) astorei_rel(&st[b], pc);
  while (aloadi(&st[tid]) < pc) {}   // blockDim==DG==256: one stamp/thread
  __syncthreads();
}

struct DecArgs {
  const float *emb, *embT, *qemb, *qembT;
  const float *Wimg_e, *bimg, *Wmod_img;
  const float *Wq_e, *bq, *Wmod_q;
  const float *Wmod, *bmod;
  const u16 *Wfus_bf; const float *bfus;
  const u16 *WfusI_bf, *WfusQ_bf;
  const u16 *Wid_bf, *Whd_bf; const float *b_dec;
  const u16 *Wfin_bf; const float *bfin;
  float *e_img, *m_img, *e_q, *m_q;
  float *a_img, *a_q, *ctx_img, *ctx_q;
  float *d_img, *d_q, *scal;
  u64 *tfs, *thdec;
  int *st; float *out; int T;
};

__global__ __launch_bounds__(256, 1) void k_dec(DecArgs A)
{
  const int b = blockIdx.x, tid = threadIdx.x;
  const int lane = tid & 63, wv = tid >> 6;
  __shared__ __align__(16) float hl[1024];
  __shared__ __align__(16) float fsl[1024];
  __shared__ float red[4];
  __shared__ float gb[16];
  __shared__ float cdec[4];
  __shared__ float aql[32];
  int pc = 0;

  // ---- P0: e_img/m_img (1 row per wave), e_q/m_q (blocks 0..31)
  {
    int l = b * 4 + wv;
    const float* er = A.emb + (size_t)l * 1024;
    float se = 0, sm = 0;
#pragma unroll
    for (int i = 0; i < 16; ++i){
      int k = lane + (i << 6);
      float x = er[k];
      se = fmaf(x, A.Wimg_e[k], se);
      sm = fmaf(x, A.Wmod_img[k], sm);
    }
    se = wred_sum(se); sm = wred_sum(sm);
    if (lane == 0){ astoref(A.e_img + l, se + A.bimg[0]); astoref(A.m_img + l, sm); }
    if (b < 32 && wv == 0){
      const float* qr = A.qemb + (size_t)b * 1024;
      float se2 = 0, sm2 = 0;
#pragma unroll
      for (int i = 0; i < 16; ++i){
        int k = lane + (i << 6);
        float x = qr[k];
        se2 = fmaf(x, A.Wq_e[k], se2);
        sm2 = fmaf(x, A.Wmod_q[k], sm2);
      }
      se2 = wred_sum(se2); sm2 = wred_sum(sm2);
      if (lane == 0){ astoref(A.e_q + b, se2 + A.bq[0]); astoref(A.m_q + b, sm2); }
    }
  }
  pc++; dbar(A.st, b, pc, tid);

  // ---- P1: block0 softmax (attention is step-invariant)
  if (b == 0){
    for (int k = tid; k < 1024; k += 256){ fsl[k] = aloadf(A.e_img + k); hl[k] = aloadf(A.m_img + k); }
    __syncthreads();
    float lm = -3.4e38f;
    for (int k = tid; k < 1024; k += 256) lm = fmaxf(lm, fsl[k]);
    float M = bred_max(lm, red, tid);
    float ls = 0, lw = 0;
    for (int k = tid; k < 1024; k += 256){
      float e = expf(fsl[k] - M);
      fsl[k] = e; ls += e; lw += e * hl[k];
    }
    float S = bred_sum(ls, red, tid);
    float W = bred_sum(lw, red, tid);
    float inv = 1.f / S;
    for (int k = tid; k < 1024; k += 256) astoref(A.a_img + k, fsl[k] * inv);
    if (tid == 0) astoref(A.scal + 2, W * inv);
    if (tid < 64){
      float ev = (lane < 32) ? aloadf(A.e_q + lane) : -3.4e38f;
      float mv = (lane < 32) ? aloadf(A.m_q + lane) : 0.f;
      float M2 = ev;
#pragma unroll
      for (int m = 32; m >= 1; m >>= 1) M2 = fmaxf(M2, __shfl_xor(M2, m, 64));
      float e = (lane < 32) ? expf(ev - M2) : 0.f;
      float S2 = wred_sum(e);
      float W2 = wred_sum(e * mv);
      if (lane < 32) astoref(A.a_q + lane, e / S2);
      if (lane == 0) astoref(A.scal + 3, W2 / S2);
    }
  }
  pc++; dbar(A.st, b, pc, tid);

  // ---- P2: ctx (once)
  if (b < 128){
    for (int k = tid; k < 1024; k += 256) hl[k] = aloadf(A.a_img + k);
    __syncthreads();
#pragma unroll
    for (int cc = 0; cc < 2; ++cc){
      int c = b * 8 + wv * 2 + cc;
      const float* eT = A.embT + (size_t)c * 1024;
      float s = 0;
#pragma unroll
      for (int i = 0; i < 16; ++i){ int l = lane + (i << 6); s = fmaf(hl[l], eT[l], s); }
      s = wred_sum(s);
      if (lane == 0) astoref(A.ctx_img + c, s);
    }
  } else {
    if (tid < 32) aql[tid] = aloadf(A.a_q + tid);
    __syncthreads();
#pragma unroll
    for (int cc = 0; cc < 2; ++cc){
      int c = (b - 128) * 8 + wv * 2 + cc;
      const float* eT = A.qembT + (size_t)c * 32;
      float s = (lane < 32) ? aql[lane] * eT[lane] : 0.f;
      s = wred_sum(s);
      if (lane == 0) astoref(A.ctx_q + c, s);
    }
  }
  pc++; dbar(A.st, b, pc, tid);

  // ---- P3: d_img/d_q (once, 1 row per wave)
  for (int k = tid; k < 1024; k += 256){ hl[k] = aloadf(A.ctx_img + k); fsl[k] = aloadf(A.ctx_q + k); }
  __syncthreads();
  {
    int r = b * 4 + wv;
    float si = wred_sum(dot1024(A.WfusI_bf + (size_t)r * 1024, hl, lane));
    float sq = wred_sum(dot1024(A.WfusQ_bf + (size_t)r * 1024, fsl, lane));
    if (lane == 0){ astoref(A.d_img + r, si); astoref(A.d_q + r, sq); }
  }
  pc++; dbar(A.st, b, pc, tid);

  // per-wave constants
  const int fr = b * 4 + wv;
  const float dimg_r = aloadf(A.d_img + fr);
  const float dq_r   = aloadf(A.d_q + fr);
  const float bfus_r = A.bfus[fr];
  const float sc2 = aloadf(A.scal + 2), sc3 = aloadf(A.scal + 3);
  const float bmod0 = A.bmod[0];
  float wmod_r[4];
#pragma unroll
  for (int i = 0; i < 4; ++i) wmod_r[i] = A.Wmod[tid + (i << 8)];

  for (int k = tid; k < 1024; k += 256) hl[k] = 0.f;
  if (tid < 4) cdec[tid] = 0.f;
  __syncthreads();

  const int gw = (b - 1) * 4 + wv;      // logits wave id (b>0): 0..1019
  const int gbase = wv * 1024 + b * 4;  // 4 gate rows per wave

  // ---- decode loop: 2 tagged round trips per step; mw computed locally
  for (int t = 0; t < A.T; ++t){
    const u32 want = (u32)(t + 1);

    // mw (identical fp sequence in every block -> identical bits)
    float part = 0;
#pragma unroll
    for (int i = 0; i < 4; ++i) part = fmaf(wmod_r[i], hl[tid + (i << 8)], part);
    float tmp = bred_sum(part, red, tid) + bmod0;
    float wi_ = tanhf(tmp + sc2), wq_ = tanhf(tmp + sc3);
    float mx = fmaxf(wi_, wq_);
    float e0 = expf(wi_ - mx), e1 = expf(wq_ - mx);
    float inv01 = 1.f / (e0 + e1);
    float mw0 = e0 * inv01, mw1 = e1 * inv01;

    // fs row (1 per wave) + publish
    {
      float s = wred_sum(dot1024(A.Wfus_bf + (size_t)fr * 1024, hl, lane));
      if (lane == 0){
        float v = tanhf(s + bfus_r + mw0 * dimg_r + mw1 * dq_r);
        astore64(&A.tfs[fr], tagpack(want, v));
      }
    }

    // logits_{t-1} = Wfin @ h_t (overlaps the fs round trip), 1020 waves
    if (b > 0 && t > 0){
      float* orow = A.out + (size_t)(t - 1) * 32000;
      int r = gw;
      for (; r + 3060 < 32000; r += 4080){
        float4 s = dot4(A.Wfin_bf, (size_t)r, 1020, hl, lane);
        if (lane == 0){
          orow[r]        = s.x + A.bfin[r];
          orow[r + 1020] = s.y + A.bfin[r + 1020];
          orow[r + 2040] = s.z + A.bfin[r + 2040];
          orow[r + 3060] = s.w + A.bfin[r + 3060];
        }
      }
      for (; r < 32000; r += 1020){
        float s = wred_sum(dot1024(A.Wfin_bf + (size_t)r * 1024, hl, lane));
        if (lane == 0) orow[r] = s + A.bfin[r];
      }
    }

    // poll fs
    {
      u64 w4[4];
#pragma unroll
      for (int k = 0; k < 4; ++k) w4[k] = aload64(&A.tfs[tid + (k << 8)]);
#pragma unroll
      for (int k = 0; k < 4; ++k){
        while ((u32)(w4[k] >> 32) != want) w4[k] = aload64(&A.tfs[tid + (k << 8)]);
        fsl[tid + (k << 8)] = __uint_as_float((u32)w4[k]);
      }
    }
    __syncthreads();

    // gates: 4 rows per wave (gate wv, h-elems b*4..b*4+3)
    {
      float4 sa = dot4(A.Wid_bf, (size_t)gbase, 1, fsl, lane);
      float4 sb = dot4(A.Whd_bf, (size_t)gbase, 1, hl,  lane);
      if (lane == 0){
        gb[wv * 4 + 0] = sa.x + sb.x + A.b_dec[gbase + 0];
        gb[wv * 4 + 1] = sa.y + sb.y + A.b_dec[gbase + 1];
        gb[wv * 4 + 2] = sa.z + sb.z + A.b_dec[gbase + 2];
        gb[wv * 4 + 3] = sa.w + sb.w + A.b_dec[gbase + 3];
      }
    }
    __syncthreads();
    if (tid < 4){
      float gi = gb[tid], gf = gb[4 + tid], gg = gb[8 + tid], go = gb[12 + tid];
      float c = sigm(gf) * cdec[tid] + sigm(gi) * tanhf(gg);
      cdec[tid] = c;
      float h = sigm(go) * tanhf(c);
      astore64(&A.thdec[b * 4 + tid], tagpack(want, h));
    }
    // poll h_{t+1}
    {
      u64 w4[4];
#pragma unroll
      for (int k = 0; k < 4; ++k) w4[k] = aload64(&A.thdec[tid + (k << 8)]);
#pragma unroll
      for (int k = 0; k < 4; ++k){
        while ((u32)(w4[k] >> 32) != want) w4[k] = aload64(&A.thdec[tid + (k << 8)]);
        hl[tid + (k << 8)] = __uint_as_float((u32)w4[k]);
      }
    }
    __syncthreads();
  }

  // final logits (h_T), all 1024 waves
  {
    float* orow = A.out + (size_t)(A.T - 1) * 32000;
    int r = b * 4 + wv;
    for (; r + 3072 < 32000; r += 4096){
      float4 s = dot4(A.Wfin_bf, (size_t)r, 1024, hl, lane);
      if (lane == 0){
        orow[r]        = s.x + A.bfin[r];
        orow[r + 1024] = s.y + A.bfin[r + 1024];
        orow[r + 2048] = s.z + A.bfin[r + 2048];
        orow[r + 3072] = s.w + A.bfin[r + 3072];
      }
    }
    for (; r < 32000; r += 1024){
      float s = wred_sum(dot1024(A.Wfin_bf + (size_t)r * 1024, hl, lane));
      if (lane == 0) orow[r] = s + A.bfin[r];
    }
  }
}

// ---------------------------------------------------------------- host
extern "C" void kernel_launch(void* const* d_in, const int* in_sizes, int n_in,
                              void* d_out, int out_size, void* d_ws, size_t ws_size,
                              hipStream_t stream)
{
  const float* img_feats = (const float*)d_in[0];
  const float* q_feats   = (const float*)d_in[1];
  const float* Wi_imgf = (const float*)d_in[2];
  const float* Wh_imgf = (const float*)d_in[3];
  const float* b_imgf  = (const float*)d_in[4];
  const float* Wi_imgb = (const float*)d_in[5];
  const float* Wh_imgb = (const float*)d_in[6];
  const float* b_imgb  = (const float*)d_in[7];
  const float* Wi_qf = (const float*)d_in[8];
  const float* Wh_qf = (const float*)d_in[9];
  const float* b_qf  = (const float*)d_in[10];
  const float* Wi_qb = (const float*)d_in[11];
  const float* Wh_qb = (const float*)d_in[12];
  const float* b_qb  = (const float*)d_in[13];
  const float* Wimg_e = (const float*)d_in[15];
  const float* bimg   = (const float*)d_in[16];
  const float* Wq_e   = (const float*)d_in[18];
  const float* bq     = (const float*)d_in[19];
  const float* Wmod   = (const float*)d_in[20];
  const float* bmod   = (const float*)d_in[21];
  const float* Wmod_img = (const float*)d_in[22];
  const float* Wmod_q   = (const float*)d_in[23];
  const float* Wfus_img = (const float*)d_in[24];
  const float* Wfus_q   = (const float*)d_in[25];
  const float* Wfus     = (const float*)d_in[26];
  const float* bfus     = (const float*)d_in[27];
  const float* Wi_dec = (const float*)d_in[28];
  const float* Wh_dec = (const float*)d_in[29];
  const float* b_dec  = (const float*)d_in[30];
  const float* Wfin = (const float*)d_in[31];
  const float* bfin = (const float*)d_in[32];
  const int T = out_size / 32000;

  char* ws = (char*)d_ws;
  size_t off = 0;
  auto alloc = [&](size_t bytes){ size_t o = off; off += (bytes + 255) & ~(size_t)255; return o; };
  const size_t oA    = alloc(1024ull * 2048 * 2);
  const size_t oWiF  = alloc(2048ull * 2048 * 2);
  const size_t oWiB  = alloc(2048ull * 2048 * 2);
  const size_t oWfin = alloc(32000ull * 1024 * 2);
  const size_t oWfu  = alloc(1024ull * 1024 * 2);
  const size_t oWfI  = alloc(1024ull * 1024 * 2);
  const size_t oWfQ  = alloc(1024ull * 1024 * 2);
  const size_t oWid  = alloc(4096ull * 1024 * 2);
  const size_t oWhd  = alloc(4096ull * 1024 * 2);
  const size_t oxpF  = alloc(1024ull * 2048 * 4);
  const size_t oxpB  = alloc(1024ull * 2048 * 4);
  const size_t oxpQF = alloc(32ull * 2048 * 4);
  const size_t oxpQB = alloc(32ull * 2048 * 4);
  const size_t oemb  = alloc(1024ull * 1024 * 4);
  const size_t oembT = alloc(1024ull * 1024 * 4);
  const size_t oqemb = alloc(32ull * 1024 * 4);
  const size_t oqembT= alloc(1024ull * 32 * 4);
  const size_t oeimg = alloc(1024 * 4);
  const size_t omimg = alloc(1024 * 4);
  const size_t oeq   = alloc(32 * 4);
  const size_t omq   = alloc(32 * 4);
  const size_t oaimg = alloc(1024 * 4);
  const size_t oaq   = alloc(32 * 4);
  const size_t octxi = alloc(1024 * 4);
  const size_t octxq = alloc(1024 * 4);
  const size_t odimg = alloc(1024 * 4);
  const size_t odq   = alloc(1024 * 4);
  const size_t oCTRL = off;
  const size_t ohcomm = alloc(4ull * 2 * 512 * 4);
  const size_t otfs   = alloc(1024 * 8);
  const size_t othdec = alloc(1024 * 8);
  const size_t odst   = alloc(256 * 4);
  const size_t oscal  = alloc(64 * 4);
  const size_t ctrlBytes = off - oCTRL;
  (void)ws_size; (void)n_in; (void)in_sizes;

  hipMemsetAsync(ws + oCTRL, 0, ctrlBytes, stream);

  auto cvt = [&](const float* s, size_t o, long n){
    int n4 = (int)(n >> 2);
    int g = (n4 + 255) / 256; if (g > 2048) g = 2048;
    k_cvt<<<dim3(g), dim3(256), 0, stream>>>(s, (u16*)(ws + o), n4);
  };
  cvt(img_feats, oA, 1024L * 2048);
  cvt(Wi_imgf, oWiF, 2048L * 2048);
  cvt(Wi_imgb, oWiB, 2048L * 2048);
  cvt(Wfin, oWfin, 32000L * 1024);
  cvt(Wfus, oWfu, 1024L * 1024);
  cvt(Wfus_img, oWfI, 1024L * 1024);
  cvt(Wfus_q, oWfQ, 1024L * 1024);
  cvt(Wi_dec, oWid, 4096L * 1024);
  cvt(Wh_dec, oWhd, 4096L * 1024);

  k_gemm_xp<<<dim3(16, 8, 2), dim3(256), 0, stream>>>(
      (const u16*)(ws + oA), (const u16*)(ws + oWiF), (const u16*)(ws + oWiB),
      b_imgf, b_imgb, (float*)(ws + oxpF), (float*)(ws + oxpB));

  k_qxp<<<dim3(32, 2), dim3(256), 0, stream>>>(
      q_feats, Wi_qf, Wi_qb, b_qf, b_qb,
      (float*)(ws + oxpQF), (float*)(ws + oxpQB));

  k_scan<<<dim3(128), dim3(256), 0, stream>>>(
      Wh_imgf, Wh_imgb, Wh_qf, Wh_qb,
      (const float*)(ws + oxpF), (const float*)(ws + oxpB),
      (const float*)(ws + oxpQF), (const float*)(ws + oxpQB),
      (float*)(ws + oemb), (float*)(ws + oembT),
      (float*)(ws + oqemb), (float*)(ws + oqembT),
      (u32*)(ws + ohcomm));

  DecArgs DA;
  DA.emb = (const float*)(ws + oemb); DA.embT = (const float*)(ws + oembT);
  DA.qemb = (const float*)(ws + oqemb); DA.qembT = (const float*)(ws + oqembT);
  DA.Wimg_e = Wimg_e; DA.bimg = bimg; DA.Wmod_img = Wmod_img;
  DA.Wq_e = Wq_e; DA.bq = bq; DA.Wmod_q = Wmod_q;
  DA.Wmod = Wmod; DA.bmod = bmod;
  DA.Wfus_bf = (const u16*)(ws + oWfu); DA.bfus = bfus;
  DA.WfusI_bf = (const u16*)(ws + oWfI); DA.WfusQ_bf = (const u16*)(ws + oWfQ);
  DA.Wid_bf = (const u16*)(ws + oWid); DA.Whd_bf = (const u16*)(ws + oWhd); DA.b_dec = b_dec;
  DA.Wfin_bf = (const u16*)(ws + oWfin); DA.bfin = bfin;
  DA.e_img = (float*)(ws + oeimg); DA.m_img = (float*)(ws + omimg);
  DA.e_q = (float*)(ws + oeq); DA.m_q = (float*)(ws + omq);
  DA.a_img = (float*)(ws + oaimg); DA.a_q = (float*)(ws + oaq);
  DA.ctx_img = (float*)(ws + octxi); DA.ctx_q = (float*)(ws + octxq);
  DA.d_img = (float*)(ws + odimg); DA.d_q = (float*)(ws + odq);
  DA.scal = (float*)(ws + oscal);
  DA.tfs = (u64*)(ws + otfs); DA.thdec = (u64*)(ws + othdec);
  DA.st = (int*)(ws + odst);
  DA.out = (float*)d_out; DA.T = T;

  k_dec<<<dim3(DG), dim3(256), 0, stream>>>(DA);
}

// Round 5
// 3830.128 us; speedup vs baseline: 1.9096x; 1.9096x over previous
//
#include <hip/hip_runtime.h>
#include <hip/hip_bf16.h>

typedef unsigned int  u32;
typedef unsigned short u16;
typedef unsigned long long u64;
typedef float f32x4 __attribute__((ext_vector_type(4)));
typedef short bf16x8 __attribute__((ext_vector_type(8)));
typedef u32 u32x4 __attribute__((ext_vector_type(4)));

#define AGENT __HIP_MEMORY_SCOPE_AGENT
__device__ inline float aloadf(const float* p){ return __hip_atomic_load(p, __ATOMIC_RELAXED, AGENT); }
__device__ inline void  astoref(float* p, float v){ __hip_atomic_store(p, v, __ATOMIC_RELAXED, AGENT); }
__device__ inline int   aloadi(const int* p){ return __hip_atomic_load(p, __ATOMIC_RELAXED, AGENT); }
__device__ inline void  astorei_rel(int* p, int v){ __hip_atomic_store(p, v, __ATOMIC_RELEASE, AGENT); }
__device__ inline u64   aload64(const u64* p){ return __hip_atomic_load(p, __ATOMIC_RELAXED, AGENT); }
__device__ inline void  astore64(u64* p, u64 v){ __hip_atomic_store(p, v, __ATOMIC_RELAXED, AGENT); }
__device__ inline void  astore32(u32* p, u32 v){ __hip_atomic_store(p, v, __ATOMIC_RELAXED, AGENT); }
__device__ inline u64   tagpack(u32 tag, float v){ return ((u64)tag << 32) | (u64)__float_as_uint(v); }

__device__ __host__ inline u16 f2bf(float f){
  u32 u = __builtin_bit_cast(u32, f);
  u += 0x7fffu + ((u >> 16) & 1u);
  return (u16)(u >> 16);
}
__device__ inline float bflo(u32 a){ return __uint_as_float(a << 16); }
__device__ inline float bfhi(u32 a){ return __uint_as_float(a & 0xffff0000u); }
__device__ inline float sigm(float x){ return 1.f/(1.f + expf(-x)); }

__device__ inline float wred_sum(float v){
#pragma unroll
  for (int m = 32; m >= 1; m >>= 1) v += __shfl_xor(v, m, 64);
  return v;
}
__device__ inline float bred_sum(float v, float* red, int tid){
  v = wred_sum(v);
  if ((tid & 63) == 0) red[tid >> 6] = v;
  __syncthreads();
  float r = red[0] + red[1] + red[2] + red[3];
  __syncthreads();
  return r;
}
__device__ inline float bred_max(float v, float* red, int tid){
#pragma unroll
  for (int m = 32; m >= 1; m >>= 1) v = fmaxf(v, __shfl_xor(v, m, 64));
  if ((tid & 63) == 0) red[tid >> 6] = v;
  __syncthreads();
  float r = fmaxf(fmaxf(red[0], red[1]), fmaxf(red[2], red[3]));
  __syncthreads();
  return r;
}

// 1024-dot, 4-elem chunks (LDS reads 2-way-aliased = free). Per-lane partial.
__device__ inline float dot1024(const u16* __restrict__ row, const float* h, int lane){
  float s = 0.f;
#pragma unroll
  for (int c = 0; c < 4; ++c){
    int e = 4 * lane + 256 * c;
    uint2 a = *(const uint2*)(row + e);
    float4 x = *(const float4*)(h + e);
    s = fmaf(bflo(a.x), x.x, s); s = fmaf(bfhi(a.x), x.y, s);
    s = fmaf(bflo(a.y), x.z, s); s = fmaf(bfhi(a.y), x.w, s);
  }
  return s;
}

// 4-row batched GEMV, h LDS reads amortized, 4 independent chains, reduced.
__device__ inline float4 dot4(const u16* __restrict__ W, size_t r, size_t rs,
                              const float* h, int lane){
  const u16* p0 = W + (r         ) * 1024;
  const u16* p1 = W + (r + rs    ) * 1024;
  const u16* p2 = W + (r + 2 * rs) * 1024;
  const u16* p3 = W + (r + 3 * rs) * 1024;
  float s0 = 0, s1 = 0, s2 = 0, s3 = 0;
#pragma unroll
  for (int c = 0; c < 4; ++c){
    int e = 4 * lane + 256 * c;
    float4 x = *(const float4*)(h + e);
    uint2 a0 = *(const uint2*)(p0 + e);
    uint2 a1 = *(const uint2*)(p1 + e);
    uint2 a2 = *(const uint2*)(p2 + e);
    uint2 a3 = *(const uint2*)(p3 + e);
    s0 = fmaf(bflo(a0.x), x.x, s0); s0 = fmaf(bfhi(a0.x), x.y, s0);
    s0 = fmaf(bflo(a0.y), x.z, s0); s0 = fmaf(bfhi(a0.y), x.w, s0);
    s1 = fmaf(bflo(a1.x), x.x, s1); s1 = fmaf(bfhi(a1.x), x.y, s1);
    s1 = fmaf(bflo(a1.y), x.z, s1); s1 = fmaf(bfhi(a1.y), x.w, s1);
    s2 = fmaf(bflo(a2.x), x.x, s2); s2 = fmaf(bfhi(a2.x), x.y, s2);
    s2 = fmaf(bflo(a2.y), x.z, s2); s2 = fmaf(bfhi(a2.y), x.w, s2);
    s3 = fmaf(bflo(a3.x), x.x, s3); s3 = fmaf(bfhi(a3.x), x.y, s3);
    s3 = fmaf(bflo(a3.y), x.z, s3); s3 = fmaf(bfhi(a3.y), x.w, s3);
  }
  s0 = wred_sum(s0); s1 = wred_sum(s1); s2 = wred_sum(s2); s3 = wred_sum(s3);
  return make_float4(s0, s1, s2, s3);
}

// ---------------------------------------------------------------- fp32 -> bf16
__global__ void k_cvt(const float* __restrict__ s, u16* __restrict__ d, int n4){
  int i = blockIdx.x * 256 + threadIdx.x;
  int stride = gridDim.x * 256;
  const float4* s4 = (const float4*)s;
  for (; i < n4; i += stride){
    float4 v = s4[i];
    ushort4 o;
    o.x = f2bf(v.x); o.y = f2bf(v.y); o.z = f2bf(v.z); o.w = f2bf(v.w);
    ((ushort4*)d)[i] = o;
  }
}

// ---------------------------------------------------------------- img xp GEMM
__global__ __launch_bounds__(256, 1) void k_gemm_xp(
    const u16* __restrict__ A,
    const u16* __restrict__ B0, const u16* __restrict__ B1,
    const float* __restrict__ bias0, const float* __restrict__ bias1,
    float* __restrict__ C0, float* __restrict__ C1)
{
  const int K = 2048, N = 2048;
  const int bx = blockIdx.x, by = blockIdx.y, z = blockIdx.z;
  const u16* B = z ? B1 : B0;
  const float* bias = z ? bias1 : bias0;
  float* C = z ? C1 : C0;
  const int tid = threadIdx.x;
  const int lane = tid & 63, wv = tid >> 6;
  const int m0 = by * 128, n0 = bx * 128;
  const int wm = (wv >> 1) * 64, wn = (wv & 1) * 64;

  __shared__ __align__(16) u16 lA[128 * 32];
  __shared__ __align__(16) u16 lB[128 * 32];

  f32x4 acc[4][4];
#pragma unroll
  for (int i = 0; i < 4; ++i)
#pragma unroll
    for (int j = 0; j < 4; ++j) acc[i][j] = (f32x4){0.f, 0.f, 0.f, 0.f};

  const int lrow = tid >> 2;
  const int lcol = (tid & 3) * 8;
  const u16* aBase = A + (size_t)(m0 + lrow) * K + lcol;
  const u16* bBase = B + (size_t)(n0 + lrow) * K + lcol;

  for (int kk = 0; kk < K; kk += 32){
#pragma unroll
    for (int io = 0; io < 2; ++io){
      __builtin_amdgcn_global_load_lds(
        (const __attribute__((address_space(1))) void*)(aBase + (size_t)io * 64 * K + kk),
        (__attribute__((address_space(3))) void*)((char*)lA + wv * 1024 + io * 4096), 16, 0, 0);
      __builtin_amdgcn_global_load_lds(
        (const __attribute__((address_space(1))) void*)(bBase + (size_t)io * 64 * K + kk),
        (__attribute__((address_space(3))) void*)((char*)lB + wv * 1024 + io * 4096), 16, 0, 0);
    }
    asm volatile("s_waitcnt vmcnt(0)");
    __syncthreads();

    bf16x8 af[4], bfr[4];
#pragma unroll
    for (int i = 0; i < 4; ++i){
      af[i]  = *(const bf16x8*)&lA[(wm + i * 16 + (lane & 15)) * 32 + (lane >> 4) * 8];
      bfr[i] = *(const bf16x8*)&lB[(wn + i * 16 + (lane & 15)) * 32 + (lane >> 4) * 8];
    }
#pragma unroll
    for (int i = 0; i < 4; ++i)
#pragma unroll
      for (int j = 0; j < 4; ++j)
        acc[i][j] = __builtin_amdgcn_mfma_f32_16x16x32_bf16(af[i], bfr[j], acc[i][j], 0, 0, 0);
    __syncthreads();
  }

  const int rbase = (lane >> 4) * 4;
  const int ccol = lane & 15;
#pragma unroll
  for (int i = 0; i < 4; ++i)
#pragma unroll
    for (int j = 0; j < 4; ++j){
      int col = n0 + wn + j * 16 + ccol;
      float bv = bias[col];
#pragma unroll
      for (int r2 = 0; r2 < 4; ++r2){
        int row = m0 + wm + i * 16 + rbase + r2;
        C[(size_t)row * N + col] = acc[i][j][r2] + bv;
      }
    }
}

// ---------------------------------------------------------------- q xp
__global__ __launch_bounds__(256, 1) void k_qxp(
    const float* __restrict__ qf,
    const float* __restrict__ W0, const float* __restrict__ W1,
    const float* __restrict__ bb0, const float* __restrict__ bb1,
    float* __restrict__ o0, float* __restrict__ o1)
{
  const int bx = blockIdx.x;
  const int z = blockIdx.y;
  const float* W = z ? W1 : W0;
  const float* bb = z ? bb1 : bb0;
  float* o = z ? o1 : o0;
  const int tid = threadIdx.x;
  __shared__ float xs[32 * 301];
  __shared__ float Ws[64 * 301];
  for (int idx = tid; idx < 32 * 300; idx += 256){
    int m = idx / 300, k = idx - m * 300;
    xs[m * 301 + k] = qf[idx];
  }
  for (int idx = tid; idx < 64 * 300; idx += 256){
    int j = idx / 300, k = idx - j * 300;
    Ws[j * 301 + k] = W[(size_t)(bx * 64 + j) * 300 + k];
  }
  __syncthreads();
  for (int i = 0; i < 8; ++i){
    int idx = tid + i * 256;
    int nl = idx >> 5, m = idx & 31;
    float s = 0;
    for (int k = 0; k < 300; ++k) s = fmaf(xs[m * 301 + k], Ws[nl * 301 + k], s);
    o[(size_t)m * 2048 + bx * 64 + nl] = s + bb[bx * 64 + nl];
  }
}

// ---------------------------------------------------------------- LSTM scans
// Weights in VGPRs (step-invariant, zero LDS traffic for them). h-exchange:
// each thread polls ONE tagged u64 (2x bf16+tag16), redistributes via LDS,
// one barrier/step. Grid = 256 blocks; active iff (b&7)<4 so each direction's
// 32 blocks land on one XCD under round-robin blockIdx->XCD (locality hint
// only; correctness is placement-independent).
__global__ __launch_bounds__(256, 1) void k_scan(
    const float* __restrict__ WhA, const float* __restrict__ WhB,
    const float* __restrict__ WhC, const float* __restrict__ WhD,
    const float* __restrict__ xpA, const float* __restrict__ xpB,
    const float* __restrict__ xpC, const float* __restrict__ xpD,
    float* __restrict__ emb, float* __restrict__ embT,
    float* __restrict__ qemb, float* __restrict__ qembT,
    u32* hcomm /* [4][2][512] u32 = tag16<<16 | bf16 */)
{
  const int b = blockIdx.x;
  const int slot = b & 7;
  if (slot >= 4) return;
  const int dir = slot;
  const int sub = b >> 3;          // 0..31
  const int tid = threadIdx.x;
  const float* Wh = dir == 0 ? WhA : dir == 1 ? WhB : dir == 2 ? WhC : WhD;
  const float* xp = dir == 0 ? xpA : dir == 1 ? xpB : dir == 2 ? xpC : xpD;
  const int L = (dir < 2) ? 1024 : 32;
  const int rev = dir & 1;
  float* oe  = (dir < 2) ? emb  : qemb;
  float* oeT = (dir < 2) ? embT : qembT;
  const int colbase = rev ? 512 : 0;
  const int eTL = (dir < 2) ? 1024 : 32;
  const int hbase = sub * 16;
  const int g = tid >> 4;        // h-element within block: e = hbase + g
  const int seg = tid & 15;      // k-chunk
  const bool pub = (seg == 0);

  __shared__ float hl[512];

  int grows[4];
#pragma unroll
  for (int gate = 0; gate < 4; ++gate) grows[gate] = gate * 512 + hbase + g;

  // one-time: weights -> registers (packed bf16 pairs)
  u32 wpk0[16], wpk1[16], wpk2[16], wpk3[16];
  {
    const float2* r0 = (const float2*)(Wh + (size_t)grows[0] * 512) + seg;
    const float2* r1 = (const float2*)(Wh + (size_t)grows[1] * 512) + seg;
    const float2* r2 = (const float2*)(Wh + (size_t)grows[2] * 512) + seg;
    const float2* r3 = (const float2*)(Wh + (size_t)grows[3] * 512) + seg;
#pragma unroll
    for (int i = 0; i < 16; ++i){
      float2 a0 = r0[16 * i], a1 = r1[16 * i], a2 = r2[16 * i], a3 = r3[16 * i];
      wpk0[i] = (u32)f2bf(a0.x) | ((u32)f2bf(a0.y) << 16);
      wpk1[i] = (u32)f2bf(a1.x) | ((u32)f2bf(a1.y) << 16);
      wpk2[i] = (u32)f2bf(a2.x) | ((u32)f2bf(a2.y) << 16);
      wpk3[i] = (u32)f2bf(a3.x) | ((u32)f2bf(a3.y) << 16);
    }
  }

  float creg = 0.f;
  float xpv[4];
  if (pub){
    int t0 = rev ? (L - 1) : 0;
#pragma unroll
    for (int gate = 0; gate < 4; ++gate) xpv[gate] = xp[(size_t)t0 * 2048 + grows[gate]];
  }

  u32* hcd = hcomm + dir * 1024;  // [2][512]

  for (int t = 0; t < L; ++t){
    const u32 want = (u32)t;      // h_t carries tag t (t=0 from memset)
    // poll ONE u64 (elements 2*tid, 2*tid+1)
    {
      const u64* hc64 = (const u64*)(hcd + (t & 1) * 512);
      u64 w = aload64(&hc64[tid]);
      while (((u32)(w >> 16) & 0xffffu) != want || (u32)(w >> 48) != want)
        w = aload64(&hc64[tid]);
      hl[2 * tid]     = bflo((u32)w);
      hl[2 * tid + 1] = bflo((u32)(w >> 32));
    }
    __syncthreads();

    float2 hreg[16];
#pragma unroll
    for (int i = 0; i < 16; ++i) hreg[i] = *(const float2*)&hl[2 * (seg + 16 * i)];
    float s0 = 0, s1 = 0, s2 = 0, s3 = 0;
#pragma unroll
    for (int i = 0; i < 16; ++i){
      float hx = hreg[i].x, hy = hreg[i].y;
      s0 = fmaf(bflo(wpk0[i]), hx, s0); s0 = fmaf(bfhi(wpk0[i]), hy, s0);
      s1 = fmaf(bflo(wpk1[i]), hx, s1); s1 = fmaf(bfhi(wpk1[i]), hy, s1);
      s2 = fmaf(bflo(wpk2[i]), hx, s2); s2 = fmaf(bfhi(wpk2[i]), hy, s2);
      s3 = fmaf(bflo(wpk3[i]), hx, s3); s3 = fmaf(bfhi(wpk3[i]), hy, s3);
    }
#pragma unroll
    for (int m = 1; m < 16; m <<= 1){
      s0 += __shfl_xor(s0, m, 64); s1 += __shfl_xor(s1, m, 64);
      s2 += __shfl_xor(s2, m, 64); s3 += __shfl_xor(s3, m, 64);
    }
    if (pub){
      const int trow = rev ? (L - 1 - t) : t;
      float gi = s0 + xpv[0], gf = s1 + xpv[1], gg = s2 + xpv[2], go = s3 + xpv[3];
      creg = sigm(gf) * creg + sigm(gi) * tanhf(gg);
      float h = sigm(go) * tanhf(creg);
      astore32(&hcd[((t + 1) & 1) * 512 + hbase + g],
               ((u32)(t + 1) << 16) | (u32)f2bf(h));   // publish FIRST
      int col = colbase + hbase + g;
      oe[(size_t)trow * 1024 + col] = h;
      oeT[(size_t)col * eTL + trow] = h;
      if (t + 1 < L){
        int tn = rev ? (L - 2 - t) : (t + 1);
#pragma unroll
        for (int gate = 0; gate < 4; ++gate) xpv[gate] = xp[(size_t)tn * 2048 + grows[gate]];
      }
    }
    // no trailing barrier: next step's successful poll implies every wave of
    // every block (publishers in all waves) finished reading hl for step t.
  }
}

// ---------------------------------------------------------------- decoder
#define DG 256
__device__ inline void dbar(int* st, int b, int pc, int tid){
  __syncthreads();
  if (tid == 0) astorei_rel(&st[b], pc);
  while (aloadi(&st[tid]) < pc) {}   // blockDim==DG==256: one stamp/thread
  __syncthreads();
}

struct DecArgs {
  const float *emb, *embT, *qemb, *qembT;
  const float *Wimg_e, *bimg, *Wmod_img;
  const float *Wq_e, *bq, *Wmod_q;
  const float *Wmod, *bmod;
  const u16 *Wfus_bf; const float *bfus;
  const u16 *WfusI_bf, *WfusQ_bf;
  const u16 *Wid_bf, *Whd_bf; const float *b_dec;
  const u16 *Wfin_bf; const float *bfin;
  float *e_img, *m_img, *e_q, *m_q;
  float *a_img, *a_q, *ctx_img, *ctx_q;
  float *d_img, *d_q, *scal;
  u64 *tfs, *thdec;
  int *st; float *out; int T;
};

__global__ __launch_bounds__(256, 1) void k_dec(DecArgs A)
{
  const int b = blockIdx.x, tid = threadIdx.x;
  const int lane = tid & 63, wv = tid >> 6;
  __shared__ __align__(16) float hl[1024];
  __shared__ __align__(16) float fsl[1024];
  __shared__ float red[4];
  __shared__ float gb[16];
  __shared__ float cdec[4];
  __shared__ float aql[32];
  int pc = 0;

  // ---- P0: e_img/m_img (1 row per wave), e_q/m_q (blocks 0..31)
  {
    int l = b * 4 + wv;
    const float* er = A.emb + (size_t)l * 1024;
    float se = 0, sm = 0;
#pragma unroll
    for (int i = 0; i < 16; ++i){
      int k = lane + (i << 6);
      float x = er[k];
      se = fmaf(x, A.Wimg_e[k], se);
      sm = fmaf(x, A.Wmod_img[k], sm);
    }
    se = wred_sum(se); sm = wred_sum(sm);
    if (lane == 0){ astoref(A.e_img + l, se + A.bimg[0]); astoref(A.m_img + l, sm); }
    if (b < 32 && wv == 0){
      const float* qr = A.qemb + (size_t)b * 1024;
      float se2 = 0, sm2 = 0;
#pragma unroll
      for (int i = 0; i < 16; ++i){
        int k = lane + (i << 6);
        float x = qr[k];
        se2 = fmaf(x, A.Wq_e[k], se2);
        sm2 = fmaf(x, A.Wmod_q[k], sm2);
      }
      se2 = wred_sum(se2); sm2 = wred_sum(sm2);
      if (lane == 0){ astoref(A.e_q + b, se2 + A.bq[0]); astoref(A.m_q + b, sm2); }
    }
  }
  pc++; dbar(A.st, b, pc, tid);

  // ---- P1: block0 softmax (attention is step-invariant)
  if (b == 0){
    for (int k = tid; k < 1024; k += 256){ fsl[k] = aloadf(A.e_img + k); hl[k] = aloadf(A.m_img + k); }
    __syncthreads();
    float lm = -3.4e38f;
    for (int k = tid; k < 1024; k += 256) lm = fmaxf(lm, fsl[k]);
    float M = bred_max(lm, red, tid);
    float ls = 0, lw = 0;
    for (int k = tid; k < 1024; k += 256){
      float e = expf(fsl[k] - M);
      fsl[k] = e; ls += e; lw += e * hl[k];
    }
    float S = bred_sum(ls, red, tid);
    float W = bred_sum(lw, red, tid);
    float inv = 1.f / S;
    for (int k = tid; k < 1024; k += 256) astoref(A.a_img + k, fsl[k] * inv);
    if (tid == 0) astoref(A.scal + 2, W * inv);
    if (tid < 64){
      float ev = (lane < 32) ? aloadf(A.e_q + lane) : -3.4e38f;
      float mv = (lane < 32) ? aloadf(A.m_q + lane) : 0.f;
      float M2 = ev;
#pragma unroll
      for (int m = 32; m >= 1; m >>= 1) M2 = fmaxf(M2, __shfl_xor(M2, m, 64));
      float e = (lane < 32) ? expf(ev - M2) : 0.f;
      float S2 = wred_sum(e);
      float W2 = wred_sum(e * mv);
      if (lane < 32) astoref(A.a_q + lane, e / S2);
      if (lane == 0) astoref(A.scal + 3, W2 / S2);
    }
  }
  pc++; dbar(A.st, b, pc, tid);

  // ---- P2: ctx (once)
  if (b < 128){
    for (int k = tid; k < 1024; k += 256) hl[k] = aloadf(A.a_img + k);
    __syncthreads();
#pragma unroll
    for (int cc = 0; cc < 2; ++cc){
      int c = b * 8 + wv * 2 + cc;
      const float* eT = A.embT + (size_t)c * 1024;
      float s = 0;
#pragma unroll
      for (int i = 0; i < 16; ++i){ int l = lane + (i << 6); s = fmaf(hl[l], eT[l], s); }
      s = wred_sum(s);
      if (lane == 0) astoref(A.ctx_img + c, s);
    }
  } else {
    if (tid < 32) aql[tid] = aloadf(A.a_q + tid);
    __syncthreads();
#pragma unroll
    for (int cc = 0; cc < 2; ++cc){
      int c = (b - 128) * 8 + wv * 2 + cc;
      const float* eT = A.qembT + (size_t)c * 32;
      float s = (lane < 32) ? aql[lane] * eT[lane] : 0.f;
      s = wred_sum(s);
      if (lane == 0) astoref(A.ctx_q + c, s);
    }
  }
  pc++; dbar(A.st, b, pc, tid);

  // ---- P3: d_img/d_q (once, 1 row per wave)
  for (int k = tid; k < 1024; k += 256){ hl[k] = aloadf(A.ctx_img + k); fsl[k] = aloadf(A.ctx_q + k); }
  __syncthreads();
  {
    int r = b * 4 + wv;
    float si = wred_sum(dot1024(A.WfusI_bf + (size_t)r * 1024, hl, lane));
    float sq = wred_sum(dot1024(A.WfusQ_bf + (size_t)r * 1024, fsl, lane));
    if (lane == 0){ astoref(A.d_img + r, si); astoref(A.d_q + r, sq); }
  }
  pc++; dbar(A.st, b, pc, tid);

  // per-wave constants
  const int fr = b * 4 + wv;
  const float dimg_r = aloadf(A.d_img + fr);
  const float dq_r   = aloadf(A.d_q + fr);
  const float bfus_r = A.bfus[fr];
  const float sc2 = aloadf(A.scal + 2), sc3 = aloadf(A.scal + 3);
  const float bmod0 = A.bmod[0];
  float wmod_r[4];
#pragma unroll
  for (int i = 0; i < 4; ++i) wmod_r[i] = A.Wmod[tid + (i << 8)];

  for (int k = tid; k < 1024; k += 256) hl[k] = 0.f;
  if (tid < 4) cdec[tid] = 0.f;
  __syncthreads();

  const int gw = (b - 1) * 4 + wv;      // logits wave id (b>0): 0..1019
  const int gbase = wv * 1024 + b * 4;  // 4 gate rows per wave

  // ---- decode loop: 2 tagged round trips per step; mw computed locally
  for (int t = 0; t < A.T; ++t){
    const u32 want = (u32)(t + 1);

    // mw (identical fp sequence in every block -> identical bits)
    float part = 0;
#pragma unroll
    for (int i = 0; i < 4; ++i) part = fmaf(wmod_r[i], hl[tid + (i << 8)], part);
    float tmp = bred_sum(part, red, tid) + bmod0;
    float wi_ = tanhf(tmp + sc2), wq_ = tanhf(tmp + sc3);
    float mx = fmaxf(wi_, wq_);
    float e0 = expf(wi_ - mx), e1 = expf(wq_ - mx);
    float inv01 = 1.f / (e0 + e1);
    float mw0 = e0 * inv01, mw1 = e1 * inv01;

    // fs row (1 per wave) + publish
    {
      float s = wred_sum(dot1024(A.Wfus_bf + (size_t)fr * 1024, hl, lane));
      if (lane == 0){
        float v = tanhf(s + bfus_r + mw0 * dimg_r + mw1 * dq_r);
        astore64(&A.tfs[fr], tagpack(want, v));
      }
    }

    // logits_{t-1} = Wfin @ h_t (overlaps the fs round trip), 1020 waves
    if (b > 0 && t > 0){
      float* orow = A.out + (size_t)(t - 1) * 32000;
      int r = gw;
      for (; r + 3060 < 32000; r += 4080){
        float4 s = dot4(A.Wfin_bf, (size_t)r, 1020, hl, lane);
        if (lane == 0){
          orow[r]        = s.x + A.bfin[r];
          orow[r + 1020] = s.y + A.bfin[r + 1020];
          orow[r + 2040] = s.z + A.bfin[r + 2040];
          orow[r + 3060] = s.w + A.bfin[r + 3060];
        }
      }
      for (; r < 32000; r += 1020){
        float s = wred_sum(dot1024(A.Wfin_bf + (size_t)r * 1024, hl, lane));
        if (lane == 0) orow[r] = s + A.bfin[r];
      }
    }

    // poll fs
    {
      u64 w4[4];
#pragma unroll
      for (int k = 0; k < 4; ++k) w4[k] = aload64(&A.tfs[tid + (k << 8)]);
#pragma unroll
      for (int k = 0; k < 4; ++k){
        while ((u32)(w4[k] >> 32) != want) w4[k] = aload64(&A.tfs[tid + (k << 8)]);
        fsl[tid + (k << 8)] = __uint_as_float((u32)w4[k]);
      }
    }
    __syncthreads();

    // gates: 4 rows per wave (gate wv, h-elems b*4..b*4+3)
    {
      float4 sa = dot4(A.Wid_bf, (size_t)gbase, 1, fsl, lane);
      float4 sb = dot4(A.Whd_bf, (size_t)gbase, 1, hl,  lane);
      if (lane == 0){
        gb[wv * 4 + 0] = sa.x + sb.x + A.b_dec[gbase + 0];
        gb[wv * 4 + 1] = sa.y + sb.y + A.b_dec[gbase + 1];
        gb[wv * 4 + 2] = sa.z + sb.z + A.b_dec[gbase + 2];
        gb[wv * 4 + 3] = sa.w + sb.w + A.b_dec[gbase + 3];
      }
    }
    __syncthreads();
    if (tid < 4){
      float gi = gb[tid], gf = gb[4 + tid], gg = gb[8 + tid], go = gb[12 + tid];
      float c = sigm(gf) * cdec[tid] + sigm(gi) * tanhf(gg);
      cdec[tid] = c;
      float h = sigm(go) * tanhf(c);
      astore64(&A.thdec[b * 4 + tid], tagpack(want, h));
    }
    // poll h_{t+1}
    {
      u64 w4[4];
#pragma unroll
      for (int k = 0; k < 4; ++k) w4[k] = aload64(&A.thdec[tid + (k << 8)]);
#pragma unroll
      for (int k = 0; k < 4; ++k){
        while ((u32)(w4[k] >> 32) != want) w4[k] = aload64(&A.thdec[tid + (k << 8)]);
        hl[tid + (k << 8)] = __uint_as_float((u32)w4[k]);
      }
    }
    __syncthreads();
  }

  // final logits (h_T), all 1024 waves
  {
    float* orow = A.out + (size_t)(A.T - 1) * 32000;
    int r = b * 4 + wv;
    for (; r + 3072 < 32000; r += 4096){
      float4 s = dot4(A.Wfin_bf, (size_t)r, 1024, hl, lane);
      if (lane == 0){
        orow[r]        = s.x + A.bfin[r];
        orow[r + 1024] = s.y + A.bfin[r + 1024];
        orow[r + 2048] = s.z + A.bfin[r + 2048];
        orow[r + 3072] = s.w + A.bfin[r + 3072];
      }
    }
    for (; r < 32000; r += 1024){
      float s = wred_sum(dot1024(A.Wfin_bf + (size_t)r * 1024, hl, lane));
      if (lane == 0) orow[r] = s + A.bfin[r];
    }
  }
}

// ---------------------------------------------------------------- host
extern "C" void kernel_launch(void* const* d_in, const int* in_sizes, int n_in,
                              void* d_out, int out_size, void* d_ws, size_t ws_size,
                              hipStream_t stream)
{
  const float* img_feats = (const float*)d_in[0];
  const float* q_feats   = (const float*)d_in[1];
  const float* Wi_imgf = (const float*)d_in[2];
  const float* Wh_imgf = (const float*)d_in[3];
  const float* b_imgf  = (const float*)d_in[4];
  const float* Wi_imgb = (const float*)d_in[5];
  const float* Wh_imgb = (const float*)d_in[6];
  const float* b_imgb  = (const float*)d_in[7];
  const float* Wi_qf = (const float*)d_in[8];
  const float* Wh_qf = (const float*)d_in[9];
  const float* b_qf  = (const float*)d_in[10];
  const float* Wi_qb = (const float*)d_in[11];
  const float* Wh_qb = (const float*)d_in[12];
  const float* b_qb  = (const float*)d_in[13];
  const float* Wimg_e = (const float*)d_in[15];
  const float* bimg   = (const float*)d_in[16];
  const float* Wq_e   = (const float*)d_in[18];
  const float* bq     = (const float*)d_in[19];
  const float* Wmod   = (const float*)d_in[20];
  const float* bmod   = (const float*)d_in[21];
  const float* Wmod_img = (const float*)d_in[22];
  const float* Wmod_q   = (const float*)d_in[23];
  const float* Wfus_img = (const float*)d_in[24];
  const float* Wfus_q   = (const float*)d_in[25];
  const float* Wfus     = (const float*)d_in[26];
  const float* bfus     = (const float*)d_in[27];
  const float* Wi_dec = (const float*)d_in[28];
  const float* Wh_dec = (const float*)d_in[29];
  const float* b_dec  = (const float*)d_in[30];
  const float* Wfin = (const float*)d_in[31];
  const float* bfin = (const float*)d_in[32];
  const int T = out_size / 32000;

  char* ws = (char*)d_ws;
  size_t off = 0;
  auto alloc = [&](size_t bytes){ size_t o = off; off += (bytes + 255) & ~(size_t)255; return o; };
  const size_t oA    = alloc(1024ull * 2048 * 2);
  const size_t oWiF  = alloc(2048ull * 2048 * 2);
  const size_t oWiB  = alloc(2048ull * 2048 * 2);
  const size_t oWfin = alloc(32000ull * 1024 * 2);
  const size_t oWfu  = alloc(1024ull * 1024 * 2);
  const size_t oWfI  = alloc(1024ull * 1024 * 2);
  const size_t oWfQ  = alloc(1024ull * 1024 * 2);
  const size_t oWid  = alloc(4096ull * 1024 * 2);
  const size_t oWhd  = alloc(4096ull * 1024 * 2);
  const size_t oxpF  = alloc(1024ull * 2048 * 4);
  const size_t oxpB  = alloc(1024ull * 2048 * 4);
  const size_t oxpQF = alloc(32ull * 2048 * 4);
  const size_t oxpQB = alloc(32ull * 2048 * 4);
  const size_t oemb  = alloc(1024ull * 1024 * 4);
  const size_t oembT = alloc(1024ull * 1024 * 4);
  const size_t oqemb = alloc(32ull * 1024 * 4);
  const size_t oqembT= alloc(1024ull * 32 * 4);
  const size_t oeimg = alloc(1024 * 4);
  const size_t omimg = alloc(1024 * 4);
  const size_t oeq   = alloc(32 * 4);
  const size_t omq   = alloc(32 * 4);
  const size_t oaimg = alloc(1024 * 4);
  const size_t oaq   = alloc(32 * 4);
  const size_t octxi = alloc(1024 * 4);
  const size_t octxq = alloc(1024 * 4);
  const size_t odimg = alloc(1024 * 4);
  const size_t odq   = alloc(1024 * 4);
  const size_t oCTRL = off;
  const size_t ohcomm = alloc(4ull * 2 * 512 * 4);
  const size_t otfs   = alloc(1024 * 8);
  const size_t othdec = alloc(1024 * 8);
  const size_t odst   = alloc(256 * 4);
  const size_t oscal  = alloc(64 * 4);
  const size_t ctrlBytes = off - oCTRL;
  (void)ws_size; (void)n_in; (void)in_sizes;

  hipMemsetAsync(ws + oCTRL, 0, ctrlBytes, stream);

  auto cvt = [&](const float* s, size_t o, long n){
    int n4 = (int)(n >> 2);
    int g = (n4 + 255) / 256; if (g > 2048) g = 2048;
    k_cvt<<<dim3(g), dim3(256), 0, stream>>>(s, (u16*)(ws + o), n4);
  };
  cvt(img_feats, oA, 1024L * 2048);
  cvt(Wi_imgf, oWiF, 2048L * 2048);
  cvt(Wi_imgb, oWiB, 2048L * 2048);
  cvt(Wfin, oWfin, 32000L * 1024);
  cvt(Wfus, oWfu, 1024L * 1024);
  cvt(Wfus_img, oWfI, 1024L * 1024);
  cvt(Wfus_q, oWfQ, 1024L * 1024);
  cvt(Wi_dec, oWid, 4096L * 1024);
  cvt(Wh_dec, oWhd, 4096L * 1024);

  k_gemm_xp<<<dim3(16, 8, 2), dim3(256), 0, stream>>>(
      (const u16*)(ws + oA), (const u16*)(ws + oWiF), (const u16*)(ws + oWiB),
      b_imgf, b_imgb, (float*)(ws + oxpF), (float*)(ws + oxpB));

  k_qxp<<<dim3(32, 2), dim3(256), 0, stream>>>(
      q_feats, Wi_qf, Wi_qb, b_qf, b_qb,
      (float*)(ws + oxpQF), (float*)(ws + oxpQB));

  k_scan<<<dim3(256), dim3(256), 0, stream>>>(
      Wh_imgf, Wh_imgb, Wh_qf, Wh_qb,
      (const float*)(ws + oxpF), (const float*)(ws + oxpB),
      (const float*)(ws + oxpQF), (const float*)(ws + oxpQB),
      (float*)(ws + oemb), (float*)(ws + oembT),
      (float*)(ws + oqemb), (float*)(ws + oqembT),
      (u32*)(ws + ohcomm));

  DecArgs DA;
  DA.emb = (const float*)(ws + oemb); DA.embT = (const float*)(ws + oembT);
  DA.qemb = (const float*)(ws + oqemb); DA.qembT = (const float*)(ws + oqembT);
  DA.Wimg_e = Wimg_e; DA.bimg = bimg; DA.Wmod_img = Wmod_img;
  DA.Wq_e = Wq_e; DA.bq = bq; DA.Wmod_q = Wmod_q;
  DA.Wmod = Wmod; DA.bmod = bmod;
  DA.Wfus_bf = (const u16*)(ws + oWfu); DA.bfus = bfus;
  DA.WfusI_bf = (const u16*)(ws + oWfI); DA.WfusQ_bf = (const u16*)(ws + oWfQ);
  DA.Wid_bf = (const u16*)(ws + oWid); DA.Whd_bf = (const u16*)(ws + oWhd); DA.b_dec = b_dec;
  DA.Wfin_bf = (const u16*)(ws + oWfin); DA.bfin = bfin;
  DA.e_img = (float*)(ws + oeimg); DA.m_img = (float*)(ws + omimg);
  DA.e_q = (float*)(ws + oeq); DA.m_q = (float*)(ws + omq);
  DA.a_img = (float*)(ws + oaimg); DA.a_q = (float*)(ws + oaq);
  DA.ctx_img = (float*)(ws + octxi); DA.ctx_q = (float*)(ws + octxq);
  DA.d_img = (float*)(ws + odimg); DA.d_q = (float*)(ws + odq);
  DA.scal = (float*)(ws + oscal);
  DA.tfs = (u64*)(ws + otfs); DA.thdec = (u64*)(ws + othdec);
  DA.st = (int*)(ws + odst);
  DA.out = (float*)d_out; DA.T = T;

  k_dec<<<dim3(DG), dim3(256), 0, stream>>>(DA);
}

// Round 6
// 3476.493 us; speedup vs baseline: 2.1038x; 1.1017x over previous
//
#include <hip/hip_runtime.h>
#include <hip/hip_bf16.h>

typedef unsigned int  u32;
typedef unsigned short u16;
typedef unsigned long long u64;
typedef float f32x4 __attribute__((ext_vector_type(4)));
typedef short bf16x8 __attribute__((ext_vector_type(8)));

#define AGENT __HIP_MEMORY_SCOPE_AGENT
__device__ inline float aloadf(const float* p){ return __hip_atomic_load(p, __ATOMIC_RELAXED, AGENT); }
__device__ inline void  astoref(float* p, float v){ __hip_atomic_store(p, v, __ATOMIC_RELAXED, AGENT); }
__device__ inline int   aloadi(const int* p){ return __hip_atomic_load(p, __ATOMIC_RELAXED, AGENT); }
__device__ inline void  astorei_rel(int* p, int v){ __hip_atomic_store(p, v, __ATOMIC_RELEASE, AGENT); }
__device__ inline u64   aload64(const u64* p){ return __hip_atomic_load(p, __ATOMIC_RELAXED, AGENT); }
__device__ inline void  astore64(u64* p, u64 v){ __hip_atomic_store(p, v, __ATOMIC_RELAXED, AGENT); }
__device__ inline void  astore32(u32* p, u32 v){ __hip_atomic_store(p, v, __ATOMIC_RELAXED, AGENT); }
__device__ inline u64   tagpack(u32 tag, float v){ return ((u64)tag << 32) | (u64)__float_as_uint(v); }

__device__ __host__ inline u16 f2bf(float f){
  u32 u = __builtin_bit_cast(u32, f);
  u += 0x7fffu + ((u >> 16) & 1u);
  return (u16)(u >> 16);
}
__device__ inline float bflo(u32 a){ return __uint_as_float(a << 16); }
__device__ inline float bfhi(u32 a){ return __uint_as_float(a & 0xffff0000u); }
__device__ inline float sigm(float x){ return 1.f/(1.f + expf(-x)); }

__device__ inline float wred_sum(float v){
#pragma unroll
  for (int m = 32; m >= 1; m >>= 1) v += __shfl_xor(v, m, 64);
  return v;
}
__device__ inline float bred_sum(float v, float* red, int tid){
  v = wred_sum(v);
  if ((tid & 63) == 0) red[tid >> 6] = v;
  __syncthreads();
  float r = red[0] + red[1] + red[2] + red[3];
  __syncthreads();
  return r;
}
__device__ inline float bred_max(float v, float* red, int tid){
#pragma unroll
  for (int m = 32; m >= 1; m >>= 1) v = fmaxf(v, __shfl_xor(v, m, 64));
  if ((tid & 63) == 0) red[tid >> 6] = v;
  __syncthreads();
  float r = fmaxf(fmaxf(red[0], red[1]), fmaxf(red[2], red[3]));
  __syncthreads();
  return r;
}

// 1024-dot, 4-elem chunks. Per-lane partial.
__device__ inline float dot1024(const u16* __restrict__ row, const float* h, int lane){
  float s = 0.f;
#pragma unroll
  for (int c = 0; c < 4; ++c){
    int e = 4 * lane + 256 * c;
    uint2 a = *(const uint2*)(row + e);
    float4 x = *(const float4*)(h + e);
    s = fmaf(bflo(a.x), x.x, s); s = fmaf(bfhi(a.x), x.y, s);
    s = fmaf(bflo(a.y), x.z, s); s = fmaf(bfhi(a.y), x.w, s);
  }
  return s;
}

// 4-row batched GEMV (rows r..r+3*rs), reduced.
__device__ inline float4 dot4(const u16* __restrict__ W, size_t r, size_t rs,
                              const float* h, int lane){
  const u16* p0 = W + (r         ) * 1024;
  const u16* p1 = W + (r + rs    ) * 1024;
  const u16* p2 = W + (r + 2 * rs) * 1024;
  const u16* p3 = W + (r + 3 * rs) * 1024;
  float s0 = 0, s1 = 0, s2 = 0, s3 = 0;
#pragma unroll
  for (int c = 0; c < 4; ++c){
    int e = 4 * lane + 256 * c;
    float4 x = *(const float4*)(h + e);
    uint2 a0 = *(const uint2*)(p0 + e);
    uint2 a1 = *(const uint2*)(p1 + e);
    uint2 a2 = *(const uint2*)(p2 + e);
    uint2 a3 = *(const uint2*)(p3 + e);
    s0 = fmaf(bflo(a0.x), x.x, s0); s0 = fmaf(bfhi(a0.x), x.y, s0);
    s0 = fmaf(bflo(a0.y), x.z, s0); s0 = fmaf(bfhi(a0.y), x.w, s0);
    s1 = fmaf(bflo(a1.x), x.x, s1); s1 = fmaf(bfhi(a1.x), x.y, s1);
    s1 = fmaf(bflo(a1.y), x.z, s1); s1 = fmaf(bfhi(a1.y), x.w, s1);
    s2 = fmaf(bflo(a2.x), x.x, s2); s2 = fmaf(bfhi(a2.x), x.y, s2);
    s2 = fmaf(bflo(a2.y), x.z, s2); s2 = fmaf(bfhi(a2.y), x.w, s2);
    s3 = fmaf(bflo(a3.x), x.x, s3); s3 = fmaf(bfhi(a3.x), x.y, s3);
    s3 = fmaf(bflo(a3.y), x.z, s3); s3 = fmaf(bfhi(a3.y), x.w, s3);
  }
  s0 = wred_sum(s0); s1 = wred_sum(s1); s2 = wred_sum(s2); s3 = wred_sum(s3);
  return make_float4(s0, s1, s2, s3);
}

// ---------------------------------------------------------------- fp32 -> bf16
__global__ void k_cvt(const float* __restrict__ s, u16* __restrict__ d, int n4){
  int i = blockIdx.x * 256 + threadIdx.x;
  int stride = gridDim.x * 256;
  const float4* s4 = (const float4*)s;
  for (; i < n4; i += stride){
    float4 v = s4[i];
    ushort4 o;
    o.x = f2bf(v.x); o.y = f2bf(v.y); o.z = f2bf(v.z); o.w = f2bf(v.w);
    ((ushort4*)d)[i] = o;
  }
}

// ---------------------------------------------------------------- img xp GEMM
__global__ __launch_bounds__(256, 1) void k_gemm_xp(
    const u16* __restrict__ A,
    const u16* __restrict__ B0, const u16* __restrict__ B1,
    const float* __restrict__ bias0, const float* __restrict__ bias1,
    float* __restrict__ C0, float* __restrict__ C1)
{
  const int K = 2048, N = 2048;
  const int bx = blockIdx.x, by = blockIdx.y, z = blockIdx.z;
  const u16* B = z ? B1 : B0;
  const float* bias = z ? bias1 : bias0;
  float* C = z ? C1 : C0;
  const int tid = threadIdx.x;
  const int lane = tid & 63, wv = tid >> 6;
  const int m0 = by * 128, n0 = bx * 128;
  const int wm = (wv >> 1) * 64, wn = (wv & 1) * 64;

  __shared__ __align__(16) u16 lA[128 * 32];
  __shared__ __align__(16) u16 lB[128 * 32];

  f32x4 acc[4][4];
#pragma unroll
  for (int i = 0; i < 4; ++i)
#pragma unroll
    for (int j = 0; j < 4; ++j) acc[i][j] = (f32x4){0.f, 0.f, 0.f, 0.f};

  const int lrow = tid >> 2;
  const int lcol = (tid & 3) * 8;
  const u16* aBase = A + (size_t)(m0 + lrow) * K + lcol;
  const u16* bBase = B + (size_t)(n0 + lrow) * K + lcol;

  for (int kk = 0; kk < K; kk += 32){
#pragma unroll
    for (int io = 0; io < 2; ++io){
      __builtin_amdgcn_global_load_lds(
        (const __attribute__((address_space(1))) void*)(aBase + (size_t)io * 64 * K + kk),
        (__attribute__((address_space(3))) void*)((char*)lA + wv * 1024 + io * 4096), 16, 0, 0);
      __builtin_amdgcn_global_load_lds(
        (const __attribute__((address_space(1))) void*)(bBase + (size_t)io * 64 * K + kk),
        (__attribute__((address_space(3))) void*)((char*)lB + wv * 1024 + io * 4096), 16, 0, 0);
    }
    asm volatile("s_waitcnt vmcnt(0)");
    __syncthreads();

    bf16x8 af[4], bfr[4];
#pragma unroll
    for (int i = 0; i < 4; ++i){
      af[i]  = *(const bf16x8*)&lA[(wm + i * 16 + (lane & 15)) * 32 + (lane >> 4) * 8];
      bfr[i] = *(const bf16x8*)&lB[(wn + i * 16 + (lane & 15)) * 32 + (lane >> 4) * 8];
    }
#pragma unroll
    for (int i = 0; i < 4; ++i)
#pragma unroll
      for (int j = 0; j < 4; ++j)
        acc[i][j] = __builtin_amdgcn_mfma_f32_16x16x32_bf16(af[i], bfr[j], acc[i][j], 0, 0, 0);
    __syncthreads();
  }

  const int rbase = (lane >> 4) * 4;
  const int ccol = lane & 15;
#pragma unroll
  for (int i = 0; i < 4; ++i)
#pragma unroll
    for (int j = 0; j < 4; ++j){
      int col = n0 + wn + j * 16 + ccol;
      float bv = bias[col];
#pragma unroll
      for (int r2 = 0; r2 < 4; ++r2){
        int row = m0 + wm + i * 16 + rbase + r2;
        C[(size_t)row * N + col] = acc[i][j][r2] + bv;
      }
    }
}

// ---------------------------------------------------------------- q xp
__global__ __launch_bounds__(256, 1) void k_qxp(
    const float* __restrict__ qf,
    const float* __restrict__ W0, const float* __restrict__ W1,
    const float* __restrict__ bb0, const float* __restrict__ bb1,
    float* __restrict__ o0, float* __restrict__ o1)
{
  const int bx = blockIdx.x;
  const int z = blockIdx.y;
  const float* W = z ? W1 : W0;
  const float* bb = z ? bb1 : bb0;
  float* o = z ? o1 : o0;
  const int tid = threadIdx.x;
  __shared__ float xs[32 * 301];
  __shared__ float Ws[64 * 301];
  for (int idx = tid; idx < 32 * 300; idx += 256){
    int m = idx / 300, k = idx - m * 300;
    xs[m * 301 + k] = qf[idx];
  }
  for (int idx = tid; idx < 64 * 300; idx += 256){
    int j = idx / 300, k = idx - j * 300;
    Ws[j * 301 + k] = W[(size_t)(bx * 64 + j) * 300 + k];
  }
  __syncthreads();
  for (int i = 0; i < 8; ++i){
    int idx = tid + i * 256;
    int nl = idx >> 5, m = idx & 31;
    float s = 0;
    for (int k = 0; k < 300; ++k) s = fmaf(xs[m * 301 + k], Ws[nl * 301 + k], s);
    o[(size_t)m * 2048 + bx * 64 + nl] = s + bb[bx * 64 + nl];
  }
}

// ---------------------------------------------------------------- LSTM scans
// VGPR weights; ONLY WAVE 0 polls (4 batched tagged u64/lane), LDS
// redistribute, 2 barriers/step (airtight). Grid 128, natural spread.
__global__ __launch_bounds__(256, 1) void k_scan(
    const float* __restrict__ WhA, const float* __restrict__ WhB,
    const float* __restrict__ WhC, const float* __restrict__ WhD,
    const float* __restrict__ xpA, const float* __restrict__ xpB,
    const float* __restrict__ xpC, const float* __restrict__ xpD,
    float* __restrict__ emb, float* __restrict__ embT,
    float* __restrict__ qemb, float* __restrict__ qembT,
    u32* hcomm /* [4][2][512] u32 = tag16<<16 | bf16 */)
{
  const int tid = threadIdx.x;
  const int dir = blockIdx.x >> 5;
  const int sub = blockIdx.x & 31;
  const float* Wh = dir == 0 ? WhA : dir == 1 ? WhB : dir == 2 ? WhC : WhD;
  const float* xp = dir == 0 ? xpA : dir == 1 ? xpB : dir == 2 ? xpC : xpD;
  const int L = (dir < 2) ? 1024 : 32;
  const int rev = dir & 1;
  float* oe  = (dir < 2) ? emb  : qemb;
  float* oeT = (dir < 2) ? embT : qembT;
  const int colbase = rev ? 512 : 0;
  const int eTL = (dir < 2) ? 1024 : 32;
  const int hbase = sub * 16;
  const int lane = tid & 63, wv = tid >> 6;
  const int g = tid >> 4;        // h-element within block
  const int seg = tid & 15;      // k-chunk
  const bool pub = (seg == 0);

  __shared__ float hl[512];

  int grows[4];
#pragma unroll
  for (int gate = 0; gate < 4; ++gate) grows[gate] = gate * 512 + hbase + g;

  // one-time: weights -> registers (packed bf16 pairs)
  u32 wpk0[16], wpk1[16], wpk2[16], wpk3[16];
  {
    const float2* r0 = (const float2*)(Wh + (size_t)grows[0] * 512) + seg;
    const float2* r1 = (const float2*)(Wh + (size_t)grows[1] * 512) + seg;
    const float2* r2 = (const float2*)(Wh + (size_t)grows[2] * 512) + seg;
    const float2* r3 = (const float2*)(Wh + (size_t)grows[3] * 512) + seg;
#pragma unroll
    for (int i = 0; i < 16; ++i){
      float2 a0 = r0[16 * i], a1 = r1[16 * i], a2 = r2[16 * i], a3 = r3[16 * i];
      wpk0[i] = (u32)f2bf(a0.x) | ((u32)f2bf(a0.y) << 16);
      wpk1[i] = (u32)f2bf(a1.x) | ((u32)f2bf(a1.y) << 16);
      wpk2[i] = (u32)f2bf(a2.x) | ((u32)f2bf(a2.y) << 16);
      wpk3[i] = (u32)f2bf(a3.x) | ((u32)f2bf(a3.y) << 16);
    }
  }

  float creg = 0.f;
  float xpv[4];
  if (pub){
    int t0 = rev ? (L - 1) : 0;
#pragma unroll
    for (int gate = 0; gate < 4; ++gate) xpv[gate] = xp[(size_t)t0 * 2048 + grows[gate]];
  }

  u32* hcd = hcomm + dir * 1024;  // [2][512]

  for (int t = 0; t < L; ++t){
    const u32 want = (u32)t;      // h_t carries tag t (t=0 via memset)
    if (wv == 0){
      const u64* hc64 = (const u64*)(hcd + (t & 1) * 512);
      u64 w[4];
#pragma unroll
      for (int j = 0; j < 4; ++j) w[j] = aload64(&hc64[lane + 64 * j]);
#pragma unroll
      for (int j = 0; j < 4; ++j){
        while (((u32)(w[j] >> 16) & 0xffffu) != want || (u32)(w[j] >> 48) != want)
          w[j] = aload64(&hc64[lane + 64 * j]);
        *(float2*)&hl[2 * (lane + 64 * j)] =
            make_float2(bflo((u32)w[j]), bflo((u32)(w[j] >> 32)));
      }
    }
    __syncthreads();                    // hl(t) ready
    float2 hreg[16];
#pragma unroll
    for (int i = 0; i < 16; ++i) hreg[i] = *(const float2*)&hl[2 * (seg + 16 * i)];
    __syncthreads();                    // all reads done before next overwrite

    float s0 = 0, s1 = 0, s2 = 0, s3 = 0;
#pragma unroll
    for (int i = 0; i < 16; ++i){
      float hx = hreg[i].x, hy = hreg[i].y;
      s0 = fmaf(bflo(wpk0[i]), hx, s0); s0 = fmaf(bfhi(wpk0[i]), hy, s0);
      s1 = fmaf(bflo(wpk1[i]), hx, s1); s1 = fmaf(bfhi(wpk1[i]), hy, s1);
      s2 = fmaf(bflo(wpk2[i]), hx, s2); s2 = fmaf(bfhi(wpk2[i]), hy, s2);
      s3 = fmaf(bflo(wpk3[i]), hx, s3); s3 = fmaf(bfhi(wpk3[i]), hy, s3);
    }
#pragma unroll
    for (int m = 1; m < 16; m <<= 1){
      s0 += __shfl_xor(s0, m, 64); s1 += __shfl_xor(s1, m, 64);
      s2 += __shfl_xor(s2, m, 64); s3 += __shfl_xor(s3, m, 64);
    }
    if (pub){
      const int trow = rev ? (L - 1 - t) : t;
      float gi = s0 + xpv[0], gf = s1 + xpv[1], gg = s2 + xpv[2], go = s3 + xpv[3];
      creg = sigm(gf) * creg + sigm(gi) * tanhf(gg);
      float h = sigm(go) * tanhf(creg);
      astore32(&hcd[((t + 1) & 1) * 512 + hbase + g],
               ((u32)(t + 1) << 16) | (u32)f2bf(h));   // publish FIRST
      int col = colbase + hbase + g;
      oe[(size_t)trow * 1024 + col] = h;
      oeT[(size_t)col * eTL + trow] = h;
      if (t + 1 < L){
        int tn = rev ? (L - 2 - t) : (t + 1);
#pragma unroll
        for (int gate = 0; gate < 4; ++gate) xpv[gate] = xp[(size_t)tn * 2048 + grows[gate]];
      }
    }
  }
}

// ---------------------------------------------------------------- decoder (64 blocks)
#define DG 64
__device__ inline void dbar(int* st, int b, int pc, int tid){
  __syncthreads();
  if (tid == 0) astorei_rel(&st[b], pc);
  if (tid < DG){
    while (aloadi(&st[tid]) < pc) {}
  }
  __syncthreads();
}

struct DecArgs {
  const float *emb, *embT, *qemb, *qembT;
  const float *Wimg_e, *bimg, *Wmod_img;
  const float *Wq_e, *bq, *Wmod_q;
  const float *Wmod, *bmod;
  const u16 *Wfus_bf; const float *bfus;
  const u16 *WfusI_bf, *WfusQ_bf;
  const u16 *Wid_bf, *Whd_bf; const float *b_dec;
  float *e_img, *m_img, *e_q, *m_q;
  float *a_img, *a_q, *ctx_img, *ctx_q;
  float *d_img, *d_q, *scal;
  u64 *tfs, *thdec;
  float *hall;           // [T][1024] fp32 h_{t+1}
  int *st; int T;
};

__global__ __launch_bounds__(256, 1) void k_dec(DecArgs A)
{
  const int b = blockIdx.x, tid = threadIdx.x;
  const int lane = tid & 63, wv = tid >> 6;
  __shared__ __align__(16) float hl[1024];
  __shared__ __align__(16) float fsl[1024];
  __shared__ float red[4];
  __shared__ float gb[4][16];
  __shared__ float cdec[16];
  __shared__ float aql[32];
  int pc = 0;

  // ---- P0: e_img/m_img 16 rows/block (4/wave); e_q/m_q blocks 0..31
  {
#pragma unroll
    for (int rr = 0; rr < 4; ++rr){
      int l = b * 16 + wv * 4 + rr;
      const float* er = A.emb + (size_t)l * 1024;
      float se = 0, sm = 0;
#pragma unroll
      for (int i = 0; i < 16; ++i){
        int k = lane + (i << 6);
        float x = er[k];
        se = fmaf(x, A.Wimg_e[k], se);
        sm = fmaf(x, A.Wmod_img[k], sm);
      }
      se = wred_sum(se); sm = wred_sum(sm);
      if (lane == 0){ astoref(A.e_img + l, se + A.bimg[0]); astoref(A.m_img + l, sm); }
    }
    if (b < 32 && wv == 0){
      const float* qr = A.qemb + (size_t)b * 1024;
      float se2 = 0, sm2 = 0;
#pragma unroll
      for (int i = 0; i < 16; ++i){
        int k = lane + (i << 6);
        float x = qr[k];
        se2 = fmaf(x, A.Wq_e[k], se2);
        sm2 = fmaf(x, A.Wmod_q[k], sm2);
      }
      se2 = wred_sum(se2); sm2 = wred_sum(sm2);
      if (lane == 0){ astoref(A.e_q + b, se2 + A.bq[0]); astoref(A.m_q + b, sm2); }
    }
  }
  pc++; dbar(A.st, b, pc, tid);

  // ---- P1: block0 softmax (attention step-invariant)
  if (b == 0){
    for (int k = tid; k < 1024; k += 256){ fsl[k] = aloadf(A.e_img + k); hl[k] = aloadf(A.m_img + k); }
    __syncthreads();
    float lm = -3.4e38f;
    for (int k = tid; k < 1024; k += 256) lm = fmaxf(lm, fsl[k]);
    float M = bred_max(lm, red, tid);
    float ls = 0, lw = 0;
    for (int k = tid; k < 1024; k += 256){
      float e = expf(fsl[k] - M);
      fsl[k] = e; ls += e; lw += e * hl[k];
    }
    float S = bred_sum(ls, red, tid);
    float W = bred_sum(lw, red, tid);
    float inv = 1.f / S;
    for (int k = tid; k < 1024; k += 256) astoref(A.a_img + k, fsl[k] * inv);
    if (tid == 0) astoref(A.scal + 2, W * inv);
    if (tid < 64){
      float ev = (lane < 32) ? aloadf(A.e_q + lane) : -3.4e38f;
      float mv = (lane < 32) ? aloadf(A.m_q + lane) : 0.f;
      float M2 = ev;
#pragma unroll
      for (int m = 32; m >= 1; m >>= 1) M2 = fmaxf(M2, __shfl_xor(M2, m, 64));
      float e = (lane < 32) ? expf(ev - M2) : 0.f;
      float S2 = wred_sum(e);
      float W2 = wred_sum(e * mv);
      if (lane < 32) astoref(A.a_q + lane, e / S2);
      if (lane == 0) astoref(A.scal + 3, W2 / S2);
    }
  }
  pc++; dbar(A.st, b, pc, tid);

  // ---- P2: ctx (16 img cols + 16 q cols per block)
  {
    for (int k = tid; k < 1024; k += 256) hl[k] = aloadf(A.a_img + k);
    if (tid < 32) aql[tid] = aloadf(A.a_q + tid);
    __syncthreads();
#pragma unroll
    for (int cc = 0; cc < 4; ++cc){
      int c = b * 16 + wv * 4 + cc;
      const float* eT = A.embT + (size_t)c * 1024;
      float s = 0;
#pragma unroll
      for (int i = 0; i < 16; ++i){ int l = lane + (i << 6); s = fmaf(hl[l], eT[l], s); }
      s = wred_sum(s);
      if (lane == 0) astoref(A.ctx_img + c, s);
      const float* qT = A.qembT + (size_t)c * 32;
      float sq = (lane < 32) ? aql[lane] * qT[lane] : 0.f;
      sq = wred_sum(sq);
      if (lane == 0) astoref(A.ctx_q + c, sq);
    }
  }
  pc++; dbar(A.st, b, pc, tid);

  // ---- P3: d_img/d_q (4 rows per wave)
  for (int k = tid; k < 1024; k += 256){ hl[k] = aloadf(A.ctx_img + k); fsl[k] = aloadf(A.ctx_q + k); }
  __syncthreads();
  {
    int r = b * 16 + wv * 4;
    float4 si = dot4(A.WfusI_bf, (size_t)r, 1, hl, lane);
    float4 sq = dot4(A.WfusQ_bf, (size_t)r, 1, fsl, lane);
    if (lane == 0){
      astoref(A.d_img + r + 0, si.x); astoref(A.d_q + r + 0, sq.x);
      astoref(A.d_img + r + 1, si.y); astoref(A.d_q + r + 1, sq.y);
      astoref(A.d_img + r + 2, si.z); astoref(A.d_q + r + 2, sq.z);
      astoref(A.d_img + r + 3, si.w); astoref(A.d_q + r + 3, sq.w);
    }
  }
  pc++; dbar(A.st, b, pc, tid);

  // per-wave constants
  const int fr = b * 16 + wv * 4;
  float dimg_r[4], dq_r[4], bfus_r[4];
#pragma unroll
  for (int rr = 0; rr < 4; ++rr){
    dimg_r[rr] = aloadf(A.d_img + fr + rr);
    dq_r[rr]   = aloadf(A.d_q + fr + rr);
    bfus_r[rr] = A.bfus[fr + rr];
  }
  const float sc2 = aloadf(A.scal + 2), sc3 = aloadf(A.scal + 3);
  const float bmod0 = A.bmod[0];
  float wmod_r[4];
#pragma unroll
  for (int i = 0; i < 4; ++i) wmod_r[i] = A.Wmod[tid + (i << 8)];

  for (int k = tid; k < 1024; k += 256) hl[k] = 0.f;
  if (tid < 16) cdec[tid] = 0.f;
  __syncthreads();

  // ---- decode loop (no logits here — deferred to k_logits)
  for (int t = 0; t < A.T; ++t){
    const u32 want = (u32)(t + 1);

    // mw computed redundantly by every block (identical fp sequence)
    float part = 0;
#pragma unroll
    for (int i = 0; i < 4; ++i) part = fmaf(wmod_r[i], hl[tid + (i << 8)], part);
    float tmp = bred_sum(part, red, tid) + bmod0;
    float wi_ = tanhf(tmp + sc2), wq_ = tanhf(tmp + sc3);
    float mx = fmaxf(wi_, wq_);
    float e0 = expf(wi_ - mx), e1 = expf(wq_ - mx);
    float inv01 = 1.f / (e0 + e1);
    float mw0 = e0 * inv01, mw1 = e1 * inv01;

    // fs rows (4 per wave) + publish
    {
      float4 sf = dot4(A.Wfus_bf, (size_t)fr, 1, hl, lane);
      if (lane == 0){
        float sv[4] = {sf.x, sf.y, sf.z, sf.w};
#pragma unroll
        for (int rr = 0; rr < 4; ++rr){
          float v = tanhf(sv[rr] + bfus_r[rr] + mw0 * dimg_r[rr] + mw1 * dq_r[rr]);
          astore64(&A.tfs[fr + rr], tagpack(want, v));
        }
      }
    }

    // poll fs -> fsl
    {
      u64 w4[4];
#pragma unroll
      for (int k = 0; k < 4; ++k) w4[k] = aload64(&A.tfs[tid + (k << 8)]);
#pragma unroll
      for (int k = 0; k < 4; ++k){
        while ((u32)(w4[k] >> 32) != want) w4[k] = aload64(&A.tfs[tid + (k << 8)]);
        fsl[tid + (k << 8)] = __uint_as_float((u32)w4[k]);
      }
    }
    __syncthreads();

    // gates: wave wv owns gate wv for this block's 16 h-elems
    {
      size_t g0 = (size_t)wv * 1024 + b * 16;
#pragma unroll
      for (int q4 = 0; q4 < 4; ++q4){
        float4 sa = dot4(A.Wid_bf, g0 + q4 * 4, 1, fsl, lane);
        float4 sb = dot4(A.Whd_bf, g0 + q4 * 4, 1, hl,  lane);
        if (lane == 0){
          gb[wv][q4 * 4 + 0] = sa.x + sb.x + A.b_dec[g0 + q4 * 4 + 0];
          gb[wv][q4 * 4 + 1] = sa.y + sb.y + A.b_dec[g0 + q4 * 4 + 1];
          gb[wv][q4 * 4 + 2] = sa.z + sb.z + A.b_dec[g0 + q4 * 4 + 2];
          gb[wv][q4 * 4 + 3] = sa.w + sb.w + A.b_dec[g0 + q4 * 4 + 3];
        }
      }
    }
    __syncthreads();    // all waves' gates + hl/fsl reads done
    if (tid < 16){
      float gi = gb[0][tid], gf = gb[1][tid], gg = gb[2][tid], go = gb[3][tid];
      float c = sigm(gf) * cdec[tid] + sigm(gi) * tanhf(gg);
      cdec[tid] = c;
      float h = sigm(go) * tanhf(c);
      astore64(&A.thdec[b * 16 + tid], tagpack(want, h));
      A.hall[(size_t)t * 1024 + b * 16 + tid] = h;   // for deferred logits
    }
    // poll h -> hl
    {
      u64 w4[4];
#pragma unroll
      for (int k = 0; k < 4; ++k) w4[k] = aload64(&A.thdec[tid + (k << 8)]);
#pragma unroll
      for (int k = 0; k < 4; ++k){
        while ((u32)(w4[k] >> 32) != want) w4[k] = aload64(&A.thdec[tid + (k << 8)]);
        hl[tid + (k << 8)] = __uint_as_float((u32)w4[k]);
      }
    }
    __syncthreads();
  }
}

// ---------------------------------------------------------------- deferred logits
// out[t][r] = Wfin[r] . h_{t+1} + bfin[r].  Wfin read ONCE (weights reused
// across all T in registers). 500 blocks x 4 waves x 16 rows = 32000.
__global__ __launch_bounds__(256, 1) void k_logits(
    const u16* __restrict__ Wfin, const float* __restrict__ bfin,
    const float* __restrict__ hall, float* __restrict__ out, int T)
{
  __shared__ u32 hp[20 * 512];
  const int tid = threadIdx.x;
  const int lane = tid & 63, wv = tid >> 6;
  const int n2 = T * 512;
  for (int idx = tid; idx < n2; idx += 256){
    float2 v = ((const float2*)hall)[idx];
    hp[idx] = (u32)f2bf(v.x) | ((u32)f2bf(v.y) << 16);
  }
  __syncthreads();
  const int gwv = blockIdx.x * 4 + wv;
#pragma unroll
  for (int gset = 0; gset < 4; ++gset){
    int r0 = gwv * 16 + gset * 4;
    uint2 wreg[4][4];
#pragma unroll
    for (int rr = 0; rr < 4; ++rr){
      const uint2* wr = (const uint2*)(Wfin + (size_t)(r0 + rr) * 1024);
#pragma unroll
      for (int c = 0; c < 4; ++c) wreg[rr][c] = wr[lane + 64 * c];
    }
    for (int t = 0; t < T; ++t){
      const uint2* hp2 = (const uint2*)&hp[t * 512];
      float s0 = 0, s1 = 0, s2 = 0, s3 = 0;
#pragma unroll
      for (int c = 0; c < 4; ++c){
        uint2 hw = hp2[lane + 64 * c];
        float h0 = bflo(hw.x), h1 = bfhi(hw.x), h2 = bflo(hw.y), h3 = bfhi(hw.y);
        uint2 a;
        a = wreg[0][c];
        s0 = fmaf(bflo(a.x), h0, s0); s0 = fmaf(bfhi(a.x), h1, s0);
        s0 = fmaf(bflo(a.y), h2, s0); s0 = fmaf(bfhi(a.y), h3, s0);
        a = wreg[1][c];
        s1 = fmaf(bflo(a.x), h0, s1); s1 = fmaf(bfhi(a.x), h1, s1);
        s1 = fmaf(bflo(a.y), h2, s1); s1 = fmaf(bfhi(a.y), h3, s1);
        a = wreg[2][c];
        s2 = fmaf(bflo(a.x), h0, s2); s2 = fmaf(bfhi(a.x), h1, s2);
        s2 = fmaf(bflo(a.y), h2, s2); s2 = fmaf(bfhi(a.y), h3, s2);
        a = wreg[3][c];
        s3 = fmaf(bflo(a.x), h0, s3); s3 = fmaf(bfhi(a.x), h1, s3);
        s3 = fmaf(bflo(a.y), h2, s3); s3 = fmaf(bfhi(a.y), h3, s3);
      }
      s0 = wred_sum(s0); s1 = wred_sum(s1); s2 = wred_sum(s2); s3 = wred_sum(s3);
      if (lane == 0){
        float* orow = out + (size_t)t * 32000;
        orow[r0 + 0] = s0 + bfin[r0 + 0];
        orow[r0 + 1] = s1 + bfin[r0 + 1];
        orow[r0 + 2] = s2 + bfin[r0 + 2];
        orow[r0 + 3] = s3 + bfin[r0 + 3];
      }
    }
  }
}

// ---------------------------------------------------------------- host
extern "C" void kernel_launch(void* const* d_in, const int* in_sizes, int n_in,
                              void* d_out, int out_size, void* d_ws, size_t ws_size,
                              hipStream_t stream)
{
  const float* img_feats = (const float*)d_in[0];
  const float* q_feats   = (const float*)d_in[1];
  const float* Wi_imgf = (const float*)d_in[2];
  const float* Wh_imgf = (const float*)d_in[3];
  const float* b_imgf  = (const float*)d_in[4];
  const float* Wi_imgb = (const float*)d_in[5];
  const float* Wh_imgb = (const float*)d_in[6];
  const float* b_imgb  = (const float*)d_in[7];
  const float* Wi_qf = (const float*)d_in[8];
  const float* Wh_qf = (const float*)d_in[9];
  const float* b_qf  = (const float*)d_in[10];
  const float* Wi_qb = (const float*)d_in[11];
  const float* Wh_qb = (const float*)d_in[12];
  const float* b_qb  = (const float*)d_in[13];
  const float* Wimg_e = (const float*)d_in[15];
  const float* bimg   = (const float*)d_in[16];
  const float* Wq_e   = (const float*)d_in[18];
  const float* bq     = (const float*)d_in[19];
  const float* Wmod   = (const float*)d_in[20];
  const float* bmod   = (const float*)d_in[21];
  const float* Wmod_img = (const float*)d_in[22];
  const float* Wmod_q   = (const float*)d_in[23];
  const float* Wfus_img = (const float*)d_in[24];
  const float* Wfus_q   = (const float*)d_in[25];
  const float* Wfus     = (const float*)d_in[26];
  const float* bfus     = (const float*)d_in[27];
  const float* Wi_dec = (const float*)d_in[28];
  const float* Wh_dec = (const float*)d_in[29];
  const float* b_dec  = (const float*)d_in[30];
  const float* Wfin = (const float*)d_in[31];
  const float* bfin = (const float*)d_in[32];
  const int T = out_size / 32000;

  char* ws = (char*)d_ws;
  size_t off = 0;
  auto alloc = [&](size_t bytes){ size_t o = off; off += (bytes + 255) & ~(size_t)255; return o; };
  const size_t oA    = alloc(1024ull * 2048 * 2);
  const size_t oWiF  = alloc(2048ull * 2048 * 2);
  const size_t oWiB  = alloc(2048ull * 2048 * 2);
  const size_t oWfin = alloc(32000ull * 1024 * 2);
  const size_t oWfu  = alloc(1024ull * 1024 * 2);
  const size_t oWfI  = alloc(1024ull * 1024 * 2);
  const size_t oWfQ  = alloc(1024ull * 1024 * 2);
  const size_t oWid  = alloc(4096ull * 1024 * 2);
  const size_t oWhd  = alloc(4096ull * 1024 * 2);
  const size_t oxpF  = alloc(1024ull * 2048 * 4);
  const size_t oxpB  = alloc(1024ull * 2048 * 4);
  const size_t oxpQF = alloc(32ull * 2048 * 4);
  const size_t oxpQB = alloc(32ull * 2048 * 4);
  const size_t oemb  = alloc(1024ull * 1024 * 4);
  const size_t oembT = alloc(1024ull * 1024 * 4);
  const size_t oqemb = alloc(32ull * 1024 * 4);
  const size_t oqembT= alloc(1024ull * 32 * 4);
  const size_t ohall = alloc(20ull * 1024 * 4);
  const size_t oeimg = alloc(1024 * 4);
  const size_t omimg = alloc(1024 * 4);
  const size_t oeq   = alloc(32 * 4);
  const size_t omq   = alloc(32 * 4);
  const size_t oaimg = alloc(1024 * 4);
  const size_t oaq   = alloc(32 * 4);
  const size_t octxi = alloc(1024 * 4);
  const size_t octxq = alloc(1024 * 4);
  const size_t odimg = alloc(1024 * 4);
  const size_t odq   = alloc(1024 * 4);
  const size_t oCTRL = off;
  const size_t ohcomm = alloc(4ull * 2 * 512 * 4);
  const size_t otfs   = alloc(1024 * 8);
  const size_t othdec = alloc(1024 * 8);
  const size_t odst   = alloc(64 * 4);
  const size_t oscal  = alloc(64 * 4);
  const size_t ctrlBytes = off - oCTRL;
  (void)ws_size; (void)n_in; (void)in_sizes;

  hipMemsetAsync(ws + oCTRL, 0, ctrlBytes, stream);

  auto cvt = [&](const float* s, size_t o, long n){
    int n4 = (int)(n >> 2);
    int g = (n4 + 255) / 256; if (g > 2048) g = 2048;
    k_cvt<<<dim3(g), dim3(256), 0, stream>>>(s, (u16*)(ws + o), n4);
  };
  cvt(img_feats, oA, 1024L * 2048);
  cvt(Wi_imgf, oWiF, 2048L * 2048);
  cvt(Wi_imgb, oWiB, 2048L * 2048);
  cvt(Wfin, oWfin, 32000L * 1024);
  cvt(Wfus, oWfu, 1024L * 1024);
  cvt(Wfus_img, oWfI, 1024L * 1024);
  cvt(Wfus_q, oWfQ, 1024L * 1024);
  cvt(Wi_dec, oWid, 4096L * 1024);
  cvt(Wh_dec, oWhd, 4096L * 1024);

  k_gemm_xp<<<dim3(16, 8, 2), dim3(256), 0, stream>>>(
      (const u16*)(ws + oA), (const u16*)(ws + oWiF), (const u16*)(ws + oWiB),
      b_imgf, b_imgb, (float*)(ws + oxpF), (float*)(ws + oxpB));

  k_qxp<<<dim3(32, 2), dim3(256), 0, stream>>>(
      q_feats, Wi_qf, Wi_qb, b_qf, b_qb,
      (float*)(ws + oxpQF), (float*)(ws + oxpQB));

  k_scan<<<dim3(128), dim3(256), 0, stream>>>(
      Wh_imgf, Wh_imgb, Wh_qf, Wh_qb,
      (const float*)(ws + oxpF), (const float*)(ws + oxpB),
      (const float*)(ws + oxpQF), (const float*)(ws + oxpQB),
      (float*)(ws + oemb), (float*)(ws + oembT),
      (float*)(ws + oqemb), (float*)(ws + oqembT),
      (u32*)(ws + ohcomm));

  DecArgs DA;
  DA.emb = (const float*)(ws + oemb); DA.embT = (const float*)(ws + oembT);
  DA.qemb = (const float*)(ws + oqemb); DA.qembT = (const float*)(ws + oqembT);
  DA.Wimg_e = Wimg_e; DA.bimg = bimg; DA.Wmod_img = Wmod_img;
  DA.Wq_e = Wq_e; DA.bq = bq; DA.Wmod_q = Wmod_q;
  DA.Wmod = Wmod; DA.bmod = bmod;
  DA.Wfus_bf = (const u16*)(ws + oWfu); DA.bfus = bfus;
  DA.WfusI_bf = (const u16*)(ws + oWfI); DA.WfusQ_bf = (const u16*)(ws + oWfQ);
  DA.Wid_bf = (const u16*)(ws + oWid); DA.Whd_bf = (const u16*)(ws + oWhd); DA.b_dec = b_dec;
  DA.e_img = (float*)(ws + oeimg); DA.m_img = (float*)(ws + omimg);
  DA.e_q = (float*)(ws + oeq); DA.m_q = (float*)(ws + omq);
  DA.a_img = (float*)(ws + oaimg); DA.a_q = (float*)(ws + oaq);
  DA.ctx_img = (float*)(ws + octxi); DA.ctx_q = (float*)(ws + octxq);
  DA.d_img = (float*)(ws + odimg); DA.d_q = (float*)(ws + odq);
  DA.scal = (float*)(ws + oscal);
  DA.tfs = (u64*)(ws + otfs); DA.thdec = (u64*)(ws + othdec);
  DA.hall = (float*)(ws + ohall);
  DA.st = (int*)(ws + odst); DA.T = T;

  k_dec<<<dim3(DG), dim3(256), 0, stream>>>(DA);

  k_logits<<<dim3(500), dim3(256), 0, stream>>>(
      (const u16*)(ws + oWfin), bfin, (const float*)(ws + ohall),
      (float*)d_out, T);
}

// Round 7
// 2405.860 us; speedup vs baseline: 3.0400x; 1.4450x over previous
//
#include <hip/hip_runtime.h>
#include <hip/hip_bf16.h>

typedef unsigned int  u32;
typedef unsigned short u16;
typedef unsigned long long u64;
typedef float f32x4 __attribute__((ext_vector_type(4)));
typedef short bf16x8 __attribute__((ext_vector_type(8)));
typedef u32 u32x4 __attribute__((ext_vector_type(4)));

#define AGENT __HIP_MEMORY_SCOPE_AGENT
__device__ inline float aloadf(const float* p){ return __hip_atomic_load(p, __ATOMIC_RELAXED, AGENT); }
__device__ inline void  astoref(float* p, float v){ __hip_atomic_store(p, v, __ATOMIC_RELAXED, AGENT); }
__device__ inline int   aloadi(const int* p){ return __hip_atomic_load(p, __ATOMIC_RELAXED, AGENT); }
__device__ inline void  astorei_rel(int* p, int v){ __hip_atomic_store(p, v, __ATOMIC_RELEASE, AGENT); }

__device__ __host__ inline u16 f2bf(float f){
  u32 u = __builtin_bit_cast(u32, f);
  u += 0x7fffu + ((u >> 16) & 1u);
  return (u16)(u >> 16);
}
__device__ inline float bflo(u32 a){ return __uint_as_float(a << 16); }
__device__ inline float bfhi(u32 a){ return __uint_as_float(a & 0xffff0000u); }

// fast transcendentals: v_exp_f32 + v_rcp_f32 (~1ulp) — fine vs bf16 noise
__device__ inline float sigm(float x){
  return __builtin_amdgcn_rcpf(1.f + __expf(-x));
}
__device__ inline float ftanh(float x){
  float xc = fminf(fmaxf(x, -15.f), 15.f);
  float e = __expf(2.f * xc);
  return (e - 1.f) * __builtin_amdgcn_rcpf(e + 1.f);
}

// device-scope WIDE poll/store: tags are per-32-bit word (tag16<<16 | bf16),
// so torn 16B reads are safe; sc0 sc1 = device-coherent (bypass L1/L2).
__device__ inline u32x4 poll4(const u32* addr, u32 want){
  u32x4 w;
  do {
    asm volatile("global_load_dwordx4 %0, %1, off sc0 sc1\n\ts_waitcnt vmcnt(0)"
                 : "=&v"(w) : "v"(addr) : "memory");
  } while ((w.x >> 16) != want || (w.y >> 16) != want ||
           (w.z >> 16) != want || (w.w >> 16) != want);
  return w;
}
__device__ inline void store4(u32* addr, u32x4 q){
  asm volatile("global_store_dwordx4 %0, %1, off sc0 sc1"
               :: "v"(addr), "v"(q) : "memory");
}

__device__ inline float wred_sum(float v){
#pragma unroll
  for (int m = 32; m >= 1; m >>= 1) v += __shfl_xor(v, m, 64);
  return v;
}
__device__ inline float bred_sum(float v, float* red, int tid){
  v = wred_sum(v);
  if ((tid & 63) == 0) red[tid >> 6] = v;
  __syncthreads();
  float r = red[0] + red[1] + red[2] + red[3];
  __syncthreads();
  return r;
}
__device__ inline float bred_max(float v, float* red, int tid){
#pragma unroll
  for (int m = 32; m >= 1; m >>= 1) v = fmaxf(v, __shfl_xor(v, m, 64));
  if ((tid & 63) == 0) red[tid >> 6] = v;
  __syncthreads();
  float r = fmaxf(fmaxf(red[0], red[1]), fmaxf(red[2], red[3]));
  __syncthreads();
  return r;
}

// 1024-dot, 4-elem chunks. Per-lane partial.
__device__ inline float dot1024(const u16* __restrict__ row, const float* h, int lane){
  float s = 0.f;
#pragma unroll
  for (int c = 0; c < 4; ++c){
    int e = 4 * lane + 256 * c;
    uint2 a = *(const uint2*)(row + e);
    float4 x = *(const float4*)(h + e);
    s = fmaf(bflo(a.x), x.x, s); s = fmaf(bfhi(a.x), x.y, s);
    s = fmaf(bflo(a.y), x.z, s); s = fmaf(bfhi(a.y), x.w, s);
  }
  return s;
}

// 4-row batched GEMV (rows r..r+3*rs), reduced.
__device__ inline float4 dot4(const u16* __restrict__ W, size_t r, size_t rs,
                              const float* h, int lane){
  const u16* p0 = W + (r         ) * 1024;
  const u16* p1 = W + (r + rs    ) * 1024;
  const u16* p2 = W + (r + 2 * rs) * 1024;
  const u16* p3 = W + (r + 3 * rs) * 1024;
  float s0 = 0, s1 = 0, s2 = 0, s3 = 0;
#pragma unroll
  for (int c = 0; c < 4; ++c){
    int e = 4 * lane + 256 * c;
    float4 x = *(const float4*)(h + e);
    uint2 a0 = *(const uint2*)(p0 + e);
    uint2 a1 = *(const uint2*)(p1 + e);
    uint2 a2 = *(const uint2*)(p2 + e);
    uint2 a3 = *(const uint2*)(p3 + e);
    s0 = fmaf(bflo(a0.x), x.x, s0); s0 = fmaf(bfhi(a0.x), x.y, s0);
    s0 = fmaf(bflo(a0.y), x.z, s0); s0 = fmaf(bfhi(a0.y), x.w, s0);
    s1 = fmaf(bflo(a1.x), x.x, s1); s1 = fmaf(bfhi(a1.x), x.y, s1);
    s1 = fmaf(bflo(a1.y), x.z, s1); s1 = fmaf(bfhi(a1.y), x.w, s1);
    s2 = fmaf(bflo(a2.x), x.x, s2); s2 = fmaf(bfhi(a2.x), x.y, s2);
    s2 = fmaf(bflo(a2.y), x.z, s2); s2 = fmaf(bfhi(a2.y), x.w, s2);
    s3 = fmaf(bflo(a3.x), x.x, s3); s3 = fmaf(bfhi(a3.x), x.y, s3);
    s3 = fmaf(bflo(a3.y), x.z, s3); s3 = fmaf(bfhi(a3.y), x.w, s3);
  }
  s0 = wred_sum(s0); s1 = wred_sum(s1); s2 = wred_sum(s2); s3 = wred_sum(s3);
  return make_float4(s0, s1, s2, s3);
}

// ---------------------------------------------------------------- fp32 -> bf16
__global__ void k_cvt(const float* __restrict__ s, u16* __restrict__ d, int n4){
  int i = blockIdx.x * 256 + threadIdx.x;
  int stride = gridDim.x * 256;
  const float4* s4 = (const float4*)s;
  for (; i < n4; i += stride){
    float4 v = s4[i];
    ushort4 o;
    o.x = f2bf(v.x); o.y = f2bf(v.y); o.z = f2bf(v.z); o.w = f2bf(v.w);
    ((ushort4*)d)[i] = o;
  }
}

// ---------------------------------------------------------------- img xp GEMM
__global__ __launch_bounds__(256, 1) void k_gemm_xp(
    const u16* __restrict__ A,
    const u16* __restrict__ B0, const u16* __restrict__ B1,
    const float* __restrict__ bias0, const float* __restrict__ bias1,
    float* __restrict__ C0, float* __restrict__ C1)
{
  const int K = 2048, N = 2048;
  const int bx = blockIdx.x, by = blockIdx.y, z = blockIdx.z;
  const u16* B = z ? B1 : B0;
  const float* bias = z ? bias1 : bias0;
  float* C = z ? C1 : C0;
  const int tid = threadIdx.x;
  const int lane = tid & 63, wv = tid >> 6;
  const int m0 = by * 128, n0 = bx * 128;
  const int wm = (wv >> 1) * 64, wn = (wv & 1) * 64;

  __shared__ __align__(16) u16 lA[128 * 32];
  __shared__ __align__(16) u16 lB[128 * 32];

  f32x4 acc[4][4];
#pragma unroll
  for (int i = 0; i < 4; ++i)
#pragma unroll
    for (int j = 0; j < 4; ++j) acc[i][j] = (f32x4){0.f, 0.f, 0.f, 0.f};

  const int lrow = tid >> 2;
  const int lcol = (tid & 3) * 8;
  const u16* aBase = A + (size_t)(m0 + lrow) * K + lcol;
  const u16* bBase = B + (size_t)(n0 + lrow) * K + lcol;

  for (int kk = 0; kk < K; kk += 32){
#pragma unroll
    for (int io = 0; io < 2; ++io){
      __builtin_amdgcn_global_load_lds(
        (const __attribute__((address_space(1))) void*)(aBase + (size_t)io * 64 * K + kk),
        (__attribute__((address_space(3))) void*)((char*)lA + wv * 1024 + io * 4096), 16, 0, 0);
      __builtin_amdgcn_global_load_lds(
        (const __attribute__((address_space(1))) void*)(bBase + (size_t)io * 64 * K + kk),
        (__attribute__((address_space(3))) void*)((char*)lB + wv * 1024 + io * 4096), 16, 0, 0);
    }
    asm volatile("s_waitcnt vmcnt(0)");
    __syncthreads();

    bf16x8 af[4], bfr[4];
#pragma unroll
    for (int i = 0; i < 4; ++i){
      af[i]  = *(const bf16x8*)&lA[(wm + i * 16 + (lane & 15)) * 32 + (lane >> 4) * 8];
      bfr[i] = *(const bf16x8*)&lB[(wn + i * 16 + (lane & 15)) * 32 + (lane >> 4) * 8];
    }
#pragma unroll
    for (int i = 0; i < 4; ++i)
#pragma unroll
      for (int j = 0; j < 4; ++j)
        acc[i][j] = __builtin_amdgcn_mfma_f32_16x16x32_bf16(af[i], bfr[j], acc[i][j], 0, 0, 0);
    __syncthreads();
  }

  const int rbase = (lane >> 4) * 4;
  const int ccol = lane & 15;
#pragma unroll
  for (int i = 0; i < 4; ++i)
#pragma unroll
    for (int j = 0; j < 4; ++j){
      int col = n0 + wn + j * 16 + ccol;
      float bv = bias[col];
#pragma unroll
      for (int r2 = 0; r2 < 4; ++r2){
        int row = m0 + wm + i * 16 + rbase + r2;
        C[(size_t)row * N + col] = acc[i][j][r2] + bv;
      }
    }
}

// ---------------------------------------------------------------- q xp
__global__ __launch_bounds__(256, 1) void k_qxp(
    const float* __restrict__ qf,
    const float* __restrict__ W0, const float* __restrict__ W1,
    const float* __restrict__ bb0, const float* __restrict__ bb1,
    float* __restrict__ o0, float* __restrict__ o1)
{
  const int bx = blockIdx.x;
  const int z = blockIdx.y;
  const float* W = z ? W1 : W0;
  const float* bb = z ? bb1 : bb0;
  float* o = z ? o1 : o0;
  const int tid = threadIdx.x;
  __shared__ float xs[32 * 301];
  __shared__ float Ws[64 * 301];
  for (int idx = tid; idx < 32 * 300; idx += 256){
    int m = idx / 300, k = idx - m * 300;
    xs[m * 301 + k] = qf[idx];
  }
  for (int idx = tid; idx < 64 * 300; idx += 256){
    int j = idx / 300, k = idx - j * 300;
    Ws[j * 301 + k] = W[(size_t)(bx * 64 + j) * 300 + k];
  }
  __syncthreads();
  for (int i = 0; i < 8; ++i){
    int idx = tid + i * 256;
    int nl = idx >> 5, m = idx & 31;
    float s = 0;
    for (int k = 0; k < 300; ++k) s = fmaf(xs[m * 301 + k], Ws[nl * 301 + k], s);
    o[(size_t)m * 2048 + bx * 64 + nl] = s + bb[bx * 64 + nl];
  }
}

// ---------------------------------------------------------------- LSTM scans
// VGPR weights; dwordx4 tagged-word exchange: 128 pollers x 1 wide load,
// 4 wide publishes/block (shfl-gathered), ONE barrier/step (publish implies,
// via the shfl-reduce data dependency, that every lane finished its LDS reads).
__global__ __launch_bounds__(256, 1) void k_scan(
    const float* __restrict__ WhA, const float* __restrict__ WhB,
    const float* __restrict__ WhC, const float* __restrict__ WhD,
    const float* __restrict__ xpA, const float* __restrict__ xpB,
    const float* __restrict__ xpC, const float* __restrict__ xpD,
    float* __restrict__ emb, float* __restrict__ embT,
    float* __restrict__ qemb, float* __restrict__ qembT,
    u32* hcomm /* [4][2][512] u32 = tag16<<16 | bf16 */)
{
  const int tid = threadIdx.x;
  const int dir = blockIdx.x >> 5;
  const int sub = blockIdx.x & 31;
  const float* Wh = dir == 0 ? WhA : dir == 1 ? WhB : dir == 2 ? WhC : WhD;
  const float* xp = dir == 0 ? xpA : dir == 1 ? xpB : dir == 2 ? xpC : xpD;
  const int L = (dir < 2) ? 1024 : 32;
  const int rev = dir & 1;
  float* oe  = (dir < 2) ? emb  : qemb;
  float* oeT = (dir < 2) ? embT : qembT;
  const int colbase = rev ? 512 : 0;
  const int eTL = (dir < 2) ? 1024 : 32;
  const int hbase = sub * 16;
  const int lane = tid & 63, wv = tid >> 6;
  const int g = tid >> 4;        // h-element within block
  const int seg = tid & 15;      // k-chunk
  const bool pub = (seg == 0);

  __shared__ float hl[512];

  int grows[4];
#pragma unroll
  for (int gate = 0; gate < 4; ++gate) grows[gate] = gate * 512 + hbase + g;

  // one-time: weights -> registers (packed bf16 pairs)
  u32 wpk0[16], wpk1[16], wpk2[16], wpk3[16];
  {
    const float2* r0 = (const float2*)(Wh + (size_t)grows[0] * 512) + seg;
    const float2* r1 = (const float2*)(Wh + (size_t)grows[1] * 512) + seg;
    const float2* r2 = (const float2*)(Wh + (size_t)grows[2] * 512) + seg;
    const float2* r3 = (const float2*)(Wh + (size_t)grows[3] * 512) + seg;
#pragma unroll
    for (int i = 0; i < 16; ++i){
      float2 a0 = r0[16 * i], a1 = r1[16 * i], a2 = r2[16 * i], a3 = r3[16 * i];
      wpk0[i] = (u32)f2bf(a0.x) | ((u32)f2bf(a0.y) << 16);
      wpk1[i] = (u32)f2bf(a1.x) | ((u32)f2bf(a1.y) << 16);
      wpk2[i] = (u32)f2bf(a2.x) | ((u32)f2bf(a2.y) << 16);
      wpk3[i] = (u32)f2bf(a3.x) | ((u32)f2bf(a3.y) << 16);
    }
  }

  float creg = 0.f;
  float xpv[4] = {0.f, 0.f, 0.f, 0.f};
  if (pub){
    int t0 = rev ? (L - 1) : 0;
#pragma unroll
    for (int gate = 0; gate < 4; ++gate) xpv[gate] = xp[(size_t)t0 * 2048 + grows[gate]];
  }

  u32* hcd = hcomm + dir * 1024;  // [2][512]

  for (int t = 0; t < L; ++t){
    const u32 want = (u32)t;      // h_t carries tag t (t=0 via memset)
    if (tid < 128){
      u32x4 w = poll4(hcd + ((t & 1) << 9) + 4 * tid, want);
      *(float4*)&hl[4 * tid] = make_float4(bflo(w.x), bflo(w.y), bflo(w.z), bflo(w.w));
    }
    __syncthreads();                    // hl(t) ready

    float2 hreg[16];
#pragma unroll
    for (int i = 0; i < 16; ++i) hreg[i] = *(const float2*)&hl[2 * (seg + 16 * i)];
    float s0 = 0, s1 = 0, s2 = 0, s3 = 0;
#pragma unroll
    for (int i = 0; i < 16; ++i){
      float hx = hreg[i].x, hy = hreg[i].y;
      s0 = fmaf(bflo(wpk0[i]), hx, s0); s0 = fmaf(bfhi(wpk0[i]), hy, s0);
      s1 = fmaf(bflo(wpk1[i]), hx, s1); s1 = fmaf(bfhi(wpk1[i]), hy, s1);
      s2 = fmaf(bflo(wpk2[i]), hx, s2); s2 = fmaf(bfhi(wpk2[i]), hy, s2);
      s3 = fmaf(bflo(wpk3[i]), hx, s3); s3 = fmaf(bfhi(wpk3[i]), hy, s3);
    }
#pragma unroll
    for (int m = 1; m < 16; m <<= 1){
      s0 += __shfl_xor(s0, m, 64); s1 += __shfl_xor(s1, m, 64);
      s2 += __shfl_xor(s2, m, 64); s3 += __shfl_xor(s3, m, 64);
    }
    u32 tg = 0;
    float hout = 0.f;
    if (pub){
      float gi = s0 + xpv[0], gf = s1 + xpv[1], gg = s2 + xpv[2], go = s3 + xpv[3];
      creg = sigm(gf) * creg + sigm(gi) * ftanh(gg);
      hout = sigm(go) * ftanh(creg);
      tg = ((u32)(t + 1) << 16) | (u32)f2bf(hout);
    }
    // gather 4 tagged words (lanes 0,16,32,48 hold g=4w..4w+3) -> lane 0 wide store
    u32 q0 = __shfl(tg, 0), q1 = __shfl(tg, 16), q2 = __shfl(tg, 32), q3 = __shfl(tg, 48);
    if (lane == 0)
      store4(hcd + (((t + 1) & 1) << 9) + hbase + 4 * wv, (u32x4){q0, q1, q2, q3});
    if (pub){
      const int trow = rev ? (L - 1 - t) : t;
      int col = colbase + hbase + g;
      oe[(size_t)trow * 1024 + col] = hout;
      oeT[(size_t)col * eTL + trow] = hout;
      if (t + 1 < L){
        int tn = rev ? (L - 2 - t) : (t + 1);
#pragma unroll
        for (int gate = 0; gate < 4; ++gate) xpv[gate] = xp[(size_t)tn * 2048 + grows[gate]];
      }
    }
    // single barrier/step: next poll success implies all blocks (incl. ours)
    // published t+1, which data-depends on every lane's hl reads at step t.
  }
}

// ---------------------------------------------------------------- decoder (64 blocks)
#define DG 64
__device__ inline void dbar(int* st, int b, int pc, int tid){
  __syncthreads();
  if (tid == 0) astorei_rel(&st[b], pc);
  if (tid < DG){
    while (aloadi(&st[tid]) < pc) {}
  }
  __syncthreads();
}

struct DecArgs {
  const float *emb, *embT, *qemb, *qembT;
  const float *Wimg_e, *bimg, *Wmod_img;
  const float *Wq_e, *bq, *Wmod_q;
  const float *Wmod, *bmod;
  const u16 *Wfus_bf; const float *bfus;
  const u16 *WfusI_bf, *WfusQ_bf;
  const u16 *Wid_bf, *Whd_bf; const float *b_dec;
  float *e_img, *m_img, *e_q, *m_q;
  float *a_img, *a_q, *ctx_img, *ctx_q;
  float *d_img, *d_q, *scal;
  u32 *tfs, *thdec;      // [1024] tagged u32 (tag16<<16 | bf16)
  float *hall;           // [T][1024] fp32 h_{t+1}
  int *st; int T;
};

__global__ __launch_bounds__(256, 1) void k_dec(DecArgs A)
{
  const int b = blockIdx.x, tid = threadIdx.x;
  const int lane = tid & 63, wv = tid >> 6;
  __shared__ __align__(16) float hl[1024];
  __shared__ __align__(16) float fsl[1024];
  __shared__ float red[4];
  __shared__ float gb[4][16];
  __shared__ float cdec[16];
  __shared__ float aql[32];
  int pc = 0;

  // ---- P0: e_img/m_img 16 rows/block (4/wave); e_q/m_q blocks 0..31
  {
#pragma unroll
    for (int rr = 0; rr < 4; ++rr){
      int l = b * 16 + wv * 4 + rr;
      const float* er = A.emb + (size_t)l * 1024;
      float se = 0, sm = 0;
#pragma unroll
      for (int i = 0; i < 16; ++i){
        int k = lane + (i << 6);
        float x = er[k];
        se = fmaf(x, A.Wimg_e[k], se);
        sm = fmaf(x, A.Wmod_img[k], sm);
      }
      se = wred_sum(se); sm = wred_sum(sm);
      if (lane == 0){ astoref(A.e_img + l, se + A.bimg[0]); astoref(A.m_img + l, sm); }
    }
    if (b < 32 && wv == 0){
      const float* qr = A.qemb + (size_t)b * 1024;
      float se2 = 0, sm2 = 0;
#pragma unroll
      for (int i = 0; i < 16; ++i){
        int k = lane + (i << 6);
        float x = qr[k];
        se2 = fmaf(x, A.Wq_e[k], se2);
        sm2 = fmaf(x, A.Wmod_q[k], sm2);
      }
      se2 = wred_sum(se2); sm2 = wred_sum(sm2);
      if (lane == 0){ astoref(A.e_q + b, se2 + A.bq[0]); astoref(A.m_q + b, sm2); }
    }
  }
  pc++; dbar(A.st, b, pc, tid);

  // ---- P1: block0 softmax (attention step-invariant)
  if (b == 0){
    for (int k = tid; k < 1024; k += 256){ fsl[k] = aloadf(A.e_img + k); hl[k] = aloadf(A.m_img + k); }
    __syncthreads();
    float lm = -3.4e38f;
    for (int k = tid; k < 1024; k += 256) lm = fmaxf(lm, fsl[k]);
    float M = bred_max(lm, red, tid);
    float ls = 0, lw = 0;
    for (int k = tid; k < 1024; k += 256){
      float e = expf(fsl[k] - M);
      fsl[k] = e; ls += e; lw += e * hl[k];
    }
    float S = bred_sum(ls, red, tid);
    float W = bred_sum(lw, red, tid);
    float inv = 1.f / S;
    for (int k = tid; k < 1024; k += 256) astoref(A.a_img + k, fsl[k] * inv);
    if (tid == 0) astoref(A.scal + 2, W * inv);
    if (tid < 64){
      float ev = (lane < 32) ? aloadf(A.e_q + lane) : -3.4e38f;
      float mv = (lane < 32) ? aloadf(A.m_q + lane) : 0.f;
      float M2 = ev;
#pragma unroll
      for (int m = 32; m >= 1; m >>= 1) M2 = fmaxf(M2, __shfl_xor(M2, m, 64));
      float e = (lane < 32) ? expf(ev - M2) : 0.f;
      float S2 = wred_sum(e);
      float W2 = wred_sum(e * mv);
      if (lane < 32) astoref(A.a_q + lane, e / S2);
      if (lane == 0) astoref(A.scal + 3, W2 / S2);
    }
  }
  pc++; dbar(A.st, b, pc, tid);

  // ---- P2: ctx (16 img cols + 16 q cols per block)
  {
    for (int k = tid; k < 1024; k += 256) hl[k] = aloadf(A.a_img + k);
    if (tid < 32) aql[tid] = aloadf(A.a_q + tid);
    __syncthreads();
#pragma unroll
    for (int cc = 0; cc < 4; ++cc){
      int c = b * 16 + wv * 4 + cc;
      const float* eT = A.embT + (size_t)c * 1024;
      float s = 0;
#pragma unroll
      for (int i = 0; i < 16; ++i){ int l = lane + (i << 6); s = fmaf(hl[l], eT[l], s); }
      s = wred_sum(s);
      if (lane == 0) astoref(A.ctx_img + c, s);
      const float* qT = A.qembT + (size_t)c * 32;
      float sq = (lane < 32) ? aql[lane] * qT[lane] : 0.f;
      sq = wred_sum(sq);
      if (lane == 0) astoref(A.ctx_q + c, sq);
    }
  }
  pc++; dbar(A.st, b, pc, tid);

  // ---- P3: d_img/d_q (4 rows per wave)
  for (int k = tid; k < 1024; k += 256){ hl[k] = aloadf(A.ctx_img + k); fsl[k] = aloadf(A.ctx_q + k); }
  __syncthreads();
  {
    int r = b * 16 + wv * 4;
    float4 si = dot4(A.WfusI_bf, (size_t)r, 1, hl, lane);
    float4 sq = dot4(A.WfusQ_bf, (size_t)r, 1, fsl, lane);
    if (lane == 0){
      astoref(A.d_img + r + 0, si.x); astoref(A.d_q + r + 0, sq.x);
      astoref(A.d_img + r + 1, si.y); astoref(A.d_q + r + 1, sq.y);
      astoref(A.d_img + r + 2, si.z); astoref(A.d_q + r + 2, sq.z);
      astoref(A.d_img + r + 3, si.w); astoref(A.d_q + r + 3, sq.w);
    }
  }
  pc++; dbar(A.st, b, pc, tid);

  // per-wave constants
  const int fr = b * 16 + wv * 4;
  float dimg_r[4], dq_r[4], bfus_r[4];
#pragma unroll
  for (int rr = 0; rr < 4; ++rr){
    dimg_r[rr] = aloadf(A.d_img + fr + rr);
    dq_r[rr]   = aloadf(A.d_q + fr + rr);
    bfus_r[rr] = A.bfus[fr + rr];
  }
  const float sc2 = aloadf(A.scal + 2), sc3 = aloadf(A.scal + 3);
  const float bmod0 = A.bmod[0];
  float wmod_r[4];
#pragma unroll
  for (int i = 0; i < 4; ++i) wmod_r[i] = A.Wmod[tid + (i << 8)];

  for (int k = tid; k < 1024; k += 256) hl[k] = 0.f;
  if (tid < 16) cdec[tid] = 0.f;
  __syncthreads();

  // ---- decode loop (logits deferred to k_logits)
  for (int t = 0; t < A.T; ++t){
    const u32 want = (u32)(t + 1);

    // mw computed redundantly by every block (identical fp sequence)
    float part = 0;
#pragma unroll
    for (int i = 0; i < 4; ++i) part = fmaf(wmod_r[i], hl[tid + (i << 8)], part);
    float tmp = bred_sum(part, red, tid) + bmod0;
    float wi_ = ftanh(tmp + sc2), wq_ = ftanh(tmp + sc3);
    float mx = fmaxf(wi_, wq_);
    float e0 = __expf(wi_ - mx), e1 = __expf(wq_ - mx);
    float inv01 = __builtin_amdgcn_rcpf(e0 + e1);
    float mw0 = e0 * inv01, mw1 = e1 * inv01;

    // fs rows (4 per wave) -> one wide tagged publish per wave
    {
      float4 sf = dot4(A.Wfus_bf, (size_t)fr, 1, hl, lane);
      if (lane == 0){
        float v0 = ftanh(sf.x + bfus_r[0] + mw0 * dimg_r[0] + mw1 * dq_r[0]);
        float v1 = ftanh(sf.y + bfus_r[1] + mw0 * dimg_r[1] + mw1 * dq_r[1]);
        float v2 = ftanh(sf.z + bfus_r[2] + mw0 * dimg_r[2] + mw1 * dq_r[2]);
        float v3 = ftanh(sf.w + bfus_r[3] + mw0 * dimg_r[3] + mw1 * dq_r[3]);
        u32x4 q = { (want << 16) | (u32)f2bf(v0), (want << 16) | (u32)f2bf(v1),
                    (want << 16) | (u32)f2bf(v2), (want << 16) | (u32)f2bf(v3) };
        store4(A.tfs + fr, q);
      }
    }

    // poll fs -> fsl (one dwordx4 per thread covers 4 values)
    {
      u32x4 w = poll4(A.tfs + 4 * tid, want);
      *(float4*)&fsl[4 * tid] = make_float4(bflo(w.x), bflo(w.y), bflo(w.z), bflo(w.w));
    }
    __syncthreads();   // A

    // gates: wave wv owns gate wv for this block's 16 h-elems
    {
      size_t g0 = (size_t)wv * 1024 + b * 16;
#pragma unroll
      for (int q4 = 0; q4 < 4; ++q4){
        float4 sa = dot4(A.Wid_bf, g0 + q4 * 4, 1, fsl, lane);
        float4 sb = dot4(A.Whd_bf, g0 + q4 * 4, 1, hl,  lane);
        if (lane == 0){
          gb[wv][q4 * 4 + 0] = sa.x + sb.x + A.b_dec[g0 + q4 * 4 + 0];
          gb[wv][q4 * 4 + 1] = sa.y + sb.y + A.b_dec[g0 + q4 * 4 + 1];
          gb[wv][q4 * 4 + 2] = sa.z + sb.z + A.b_dec[g0 + q4 * 4 + 2];
          gb[wv][q4 * 4 + 3] = sa.w + sb.w + A.b_dec[g0 + q4 * 4 + 3];
        }
      }
    }
    __syncthreads();   // B
    u32 tg = 0;
    if (tid < 16){
      float gi = gb[0][tid], gf = gb[1][tid], gg = gb[2][tid], go = gb[3][tid];
      float c = sigm(gf) * cdec[tid] + sigm(gi) * ftanh(gg);
      cdec[tid] = c;
      float h = sigm(go) * ftanh(c);
      tg = (want << 16) | (u32)f2bf(h);
      A.hall[(size_t)t * 1024 + b * 16 + tid] = h;   // exact h for logits
    }
    if (wv == 0){
      u32 q0 = __shfl(tg, 4 * lane + 0), q1 = __shfl(tg, 4 * lane + 1);
      u32 q2 = __shfl(tg, 4 * lane + 2), q3 = __shfl(tg, 4 * lane + 3);
      if (lane < 4) store4(A.thdec + b * 16 + 4 * lane, (u32x4){q0, q1, q2, q3});
    }
    // poll h -> hl
    {
      u32x4 w = poll4(A.thdec + 4 * tid, want);
      *(float4*)&hl[4 * tid] = make_float4(bflo(w.x), bflo(w.y), bflo(w.z), bflo(w.w));
    }
    __syncthreads();   // C
  }
}

// ---------------------------------------------------------------- deferred logits
__global__ __launch_bounds__(256, 1) void k_logits(
    const u16* __restrict__ Wfin, const float* __restrict__ bfin,
    const float* __restrict__ hall, float* __restrict__ out, int T)
{
  __shared__ u32 hp[20 * 512];
  const int tid = threadIdx.x;
  const int lane = tid & 63, wv = tid >> 6;
  const int n2 = T * 512;
  for (int idx = tid; idx < n2; idx += 256){
    float2 v = ((const float2*)hall)[idx];
    hp[idx] = (u32)f2bf(v.x) | ((u32)f2bf(v.y) << 16);
  }
  __syncthreads();
  const int gwv = blockIdx.x * 4 + wv;
#pragma unroll
  for (int gset = 0; gset < 4; ++gset){
    int r0 = gwv * 16 + gset * 4;
    uint2 wreg[4][4];
#pragma unroll
    for (int rr = 0; rr < 4; ++rr){
      const uint2* wr = (const uint2*)(Wfin + (size_t)(r0 + rr) * 1024);
#pragma unroll
      for (int c = 0; c < 4; ++c) wreg[rr][c] = wr[lane + 64 * c];
    }
    for (int t = 0; t < T; ++t){
      const uint2* hp2 = (const uint2*)&hp[t * 512];
      float s0 = 0, s1 = 0, s2 = 0, s3 = 0;
#pragma unroll
      for (int c = 0; c < 4; ++c){
        uint2 hw = hp2[lane + 64 * c];
        float h0 = bflo(hw.x), h1 = bfhi(hw.x), h2 = bflo(hw.y), h3 = bfhi(hw.y);
        uint2 a;
        a = wreg[0][c];
        s0 = fmaf(bflo(a.x), h0, s0); s0 = fmaf(bfhi(a.x), h1, s0);
        s0 = fmaf(bflo(a.y), h2, s0); s0 = fmaf(bfhi(a.y), h3, s0);
        a = wreg[1][c];
        s1 = fmaf(bflo(a.x), h0, s1); s1 = fmaf(bfhi(a.x), h1, s1);
        s1 = fmaf(bflo(a.y), h2, s1); s1 = fmaf(bfhi(a.y), h3, s1);
        a = wreg[2][c];
        s2 = fmaf(bflo(a.x), h0, s2); s2 = fmaf(bfhi(a.x), h1, s2);
        s2 = fmaf(bflo(a.y), h2, s2); s2 = fmaf(bfhi(a.y), h3, s2);
        a = wreg[3][c];
        s3 = fmaf(bflo(a.x), h0, s3); s3 = fmaf(bfhi(a.x), h1, s3);
        s3 = fmaf(bflo(a.y), h2, s3); s3 = fmaf(bfhi(a.y), h3, s3);
      }
      s0 = wred_sum(s0); s1 = wred_sum(s1); s2 = wred_sum(s2); s3 = wred_sum(s3);
      if (lane == 0){
        float* orow = out + (size_t)t * 32000;
        orow[r0 + 0] = s0 + bfin[r0 + 0];
        orow[r0 + 1] = s1 + bfin[r0 + 1];
        orow[r0 + 2] = s2 + bfin[r0 + 2];
        orow[r0 + 3] = s3 + bfin[r0 + 3];
      }
    }
  }
}

// ---------------------------------------------------------------- host
extern "C" void kernel_launch(void* const* d_in, const int* in_sizes, int n_in,
                              void* d_out, int out_size, void* d_ws, size_t ws_size,
                              hipStream_t stream)
{
  const float* img_feats = (const float*)d_in[0];
  const float* q_feats   = (const float*)d_in[1];
  const float* Wi_imgf = (const float*)d_in[2];
  const float* Wh_imgf = (const float*)d_in[3];
  const float* b_imgf  = (const float*)d_in[4];
  const float* Wi_imgb = (const float*)d_in[5];
  const float* Wh_imgb = (const float*)d_in[6];
  const float* b_imgb  = (const float*)d_in[7];
  const float* Wi_qf = (const float*)d_in[8];
  const float* Wh_qf = (const float*)d_in[9];
  const float* b_qf  = (const float*)d_in[10];
  const float* Wi_qb = (const float*)d_in[11];
  const float* Wh_qb = (const float*)d_in[12];
  const float* b_qb  = (const float*)d_in[13];
  const float* Wimg_e = (const float*)d_in[15];
  const float* bimg   = (const float*)d_in[16];
  const float* Wq_e   = (const float*)d_in[18];
  const float* bq     = (const float*)d_in[19];
  const float* Wmod   = (const float*)d_in[20];
  const float* bmod   = (const float*)d_in[21];
  const float* Wmod_img = (const float*)d_in[22];
  const float* Wmod_q   = (const float*)d_in[23];
  const float* Wfus_img = (const float*)d_in[24];
  const float* Wfus_q   = (const float*)d_in[25];
  const float* Wfus     = (const float*)d_in[26];
  const float* bfus     = (const float*)d_in[27];
  const float* Wi_dec = (const float*)d_in[28];
  const float* Wh_dec = (const float*)d_in[29];
  const float* b_dec  = (const float*)d_in[30];
  const float* Wfin = (const float*)d_in[31];
  const float* bfin = (const float*)d_in[32];
  const int T = out_size / 32000;

  char* ws = (char*)d_ws;
  size_t off = 0;
  auto alloc = [&](size_t bytes){ size_t o = off; off += (bytes + 255) & ~(size_t)255; return o; };
  const size_t oA    = alloc(1024ull * 2048 * 2);
  const size_t oWiF  = alloc(2048ull * 2048 * 2);
  const size_t oWiB  = alloc(2048ull * 2048 * 2);
  const size_t oWfin = alloc(32000ull * 1024 * 2);
  const size_t oWfu  = alloc(1024ull * 1024 * 2);
  const size_t oWfI  = alloc(1024ull * 1024 * 2);
  const size_t oWfQ  = alloc(1024ull * 1024 * 2);
  const size_t oWid  = alloc(4096ull * 1024 * 2);
  const size_t oWhd  = alloc(4096ull * 1024 * 2);
  const size_t oxpF  = alloc(1024ull * 2048 * 4);
  const size_t oxpB  = alloc(1024ull * 2048 * 4);
  const size_t oxpQF = alloc(32ull * 2048 * 4);
  const size_t oxpQB = alloc(32ull * 2048 * 4);
  const size_t oemb  = alloc(1024ull * 1024 * 4);
  const size_t oembT = alloc(1024ull * 1024 * 4);
  const size_t oqemb = alloc(32ull * 1024 * 4);
  const size_t oqembT= alloc(1024ull * 32 * 4);
  const size_t ohall = alloc(20ull * 1024 * 4);
  const size_t oeimg = alloc(1024 * 4);
  const size_t omimg = alloc(1024 * 4);
  const size_t oeq   = alloc(32 * 4);
  const size_t omq   = alloc(32 * 4);
  const size_t oaimg = alloc(1024 * 4);
  const size_t oaq   = alloc(32 * 4);
  const size_t octxi = alloc(1024 * 4);
  const size_t octxq = alloc(1024 * 4);
  const size_t odimg = alloc(1024 * 4);
  const size_t odq   = alloc(1024 * 4);
  const size_t oCTRL = off;
  const size_t ohcomm = alloc(4ull * 2 * 512 * 4);
  const size_t otfs   = alloc(1024 * 4);
  const size_t othdec = alloc(1024 * 4);
  const size_t odst   = alloc(64 * 4);
  const size_t oscal  = alloc(64 * 4);
  const size_t ctrlBytes = off - oCTRL;
  (void)ws_size; (void)n_in; (void)in_sizes;

  hipMemsetAsync(ws + oCTRL, 0, ctrlBytes, stream);

  auto cvt = [&](const float* s, size_t o, long n){
    int n4 = (int)(n >> 2);
    int g = (n4 + 255) / 256; if (g > 2048) g = 2048;
    k_cvt<<<dim3(g), dim3(256), 0, stream>>>(s, (u16*)(ws + o), n4);
  };
  cvt(img_feats, oA, 1024L * 2048);
  cvt(Wi_imgf, oWiF, 2048L * 2048);
  cvt(Wi_imgb, oWiB, 2048L * 2048);
  cvt(Wfin, oWfin, 32000L * 1024);
  cvt(Wfus, oWfu, 1024L * 1024);
  cvt(Wfus_img, oWfI, 1024L * 1024);
  cvt(Wfus_q, oWfQ, 1024L * 1024);
  cvt(Wi_dec, oWid, 4096L * 1024);
  cvt(Wh_dec, oWhd, 4096L * 1024);

  k_gemm_xp<<<dim3(16, 8, 2), dim3(256), 0, stream>>>(
      (const u16*)(ws + oA), (const u16*)(ws + oWiF), (const u16*)(ws + oWiB),
      b_imgf, b_imgb, (float*)(ws + oxpF), (float*)(ws + oxpB));

  k_qxp<<<dim3(32, 2), dim3(256), 0, stream>>>(
      q_feats, Wi_qf, Wi_qb, b_qf, b_qb,
      (float*)(ws + oxpQF), (float*)(ws + oxpQB));

  k_scan<<<dim3(128), dim3(256), 0, stream>>>(
      Wh_imgf, Wh_imgb, Wh_qf, Wh_qb,
      (const float*)(ws + oxpF), (const float*)(ws + oxpB),
      (const float*)(ws + oxpQF), (const float*)(ws + oxpQB),
      (float*)(ws + oemb), (float*)(ws + oembT),
      (float*)(ws + oqemb), (float*)(ws + oqembT),
      (u32*)(ws + ohcomm));

  DecArgs DA;
  DA.emb = (const float*)(ws + oemb); DA.embT = (const float*)(ws + oembT);
  DA.qemb = (const float*)(ws + oqemb); DA.qembT = (const float*)(ws + oqembT);
  DA.Wimg_e = Wimg_e; DA.bimg = bimg; DA.Wmod_img = Wmod_img;
  DA.Wq_e = Wq_e; DA.bq = bq; DA.Wmod_q = Wmod_q;
  DA.Wmod = Wmod; DA.bmod = bmod;
  DA.Wfus_bf = (const u16*)(ws + oWfu); DA.bfus = bfus;
  DA.WfusI_bf = (const u16*)(ws + oWfI); DA.WfusQ_bf = (const u16*)(ws + oWfQ);
  DA.Wid_bf = (const u16*)(ws + oWid); DA.Whd_bf = (const u16*)(ws + oWhd); DA.b_dec = b_dec;
  DA.e_img = (float*)(ws + oeimg); DA.m_img = (float*)(ws + omimg);
  DA.e_q = (float*)(ws + oeq); DA.m_q = (float*)(ws + omq);
  DA.a_img = (float*)(ws + oaimg); DA.a_q = (float*)(ws + oaq);
  DA.ctx_img = (float*)(ws + octxi); DA.ctx_q = (float*)(ws + octxq);
  DA.d_img = (float*)(ws + odimg); DA.d_q = (float*)(ws + odq);
  DA.scal = (float*)(ws + oscal);
  DA.tfs = (u32*)(ws + otfs); DA.thdec = (u32*)(ws + othdec);
  DA.hall = (float*)(ws + ohall);
  DA.st = (int*)(ws + odst); DA.T = T;

  k_dec<<<dim3(DG), dim3(256), 0, stream>>>(DA);

  k_logits<<<dim3(500), dim3(256), 0, stream>>>(
      (const u16*)(ws + oWfin), bfin, (const float*)(ws + ohall),
      (float*)d_out, T);
}

// Round 8
// 2059.295 us; speedup vs baseline: 3.5516x; 1.1683x over previous
//
#include <hip/hip_runtime.h>
#include <hip/hip_bf16.h>

typedef unsigned int  u32;
typedef unsigned short u16;
typedef unsigned long long u64;
typedef float f32x4 __attribute__((ext_vector_type(4)));
typedef short bf16x8 __attribute__((ext_vector_type(8)));
typedef u32 u32x4 __attribute__((ext_vector_type(4)));

#define AGENT __HIP_MEMORY_SCOPE_AGENT
__device__ inline float aloadf(const float* p){ return __hip_atomic_load(p, __ATOMIC_RELAXED, AGENT); }
__device__ inline void  astoref(float* p, float v){ __hip_atomic_store(p, v, __ATOMIC_RELAXED, AGENT); }
__device__ inline int   aloadi(const int* p){ return __hip_atomic_load(p, __ATOMIC_RELAXED, AGENT); }
__device__ inline void  astorei_rel(int* p, int v){ __hip_atomic_store(p, v, __ATOMIC_RELEASE, AGENT); }

__device__ __host__ inline u16 f2bf(float f){
  u32 u = __builtin_bit_cast(u32, f);
  u += 0x7fffu + ((u >> 16) & 1u);
  return (u16)(u >> 16);
}
__device__ inline float bflo(u32 a){ return __uint_as_float(a << 16); }
__device__ inline float bfhi(u32 a){ return __uint_as_float(a & 0xffff0000u); }

// fast transcendentals: v_exp_f32 + v_rcp_f32 (~1ulp) — fine vs bf16 noise
__device__ inline float sigm(float x){
  return __builtin_amdgcn_rcpf(1.f + __expf(-x));
}
__device__ inline float ftanh(float x){
  float xc = fminf(fmaxf(x, -15.f), 15.f);
  float e = __expf(2.f * xc);
  return (e - 1.f) * __builtin_amdgcn_rcpf(e + 1.f);
}

// device-scope WIDE poll/store: tags are per-32-bit word (tag16<<16 | bf16),
// so torn 16B reads are safe.  sc0 sc1 = device-coherent (coherence point);
// sc0 only = L1-bypassed, served by this XCD's L2 (intra-XCD coherent).
__device__ inline u32x4 poll4(const u32* addr, u32 want){
  u32x4 w;
  do {
    asm volatile("global_load_dwordx4 %0, %1, off sc0 sc1\n\ts_waitcnt vmcnt(0)"
                 : "=&v"(w) : "v"(addr) : "memory");
  } while ((w.x >> 16) != want || (w.y >> 16) != want ||
           (w.z >> 16) != want || (w.w >> 16) != want);
  return w;
}
// dual-mirror poll: try the local (same-XCD L2) mirror first — cheap (~200cy)
// even when permanently stale; the global mirror guarantees progress, so
// correctness does NOT depend on block->XCD placement.
__device__ inline u32x4 poll4_dual(const u32* loc, const u32* glob, u32 want){
  u32x4 w;
  for (;;){
    asm volatile("global_load_dwordx4 %0, %1, off sc0\n\ts_waitcnt vmcnt(0)"
                 : "=&v"(w) : "v"(loc) : "memory");
    if ((w.x >> 16) == want && (w.y >> 16) == want &&
        (w.z >> 16) == want && (w.w >> 16) == want) return w;
    asm volatile("global_load_dwordx4 %0, %1, off sc0 sc1\n\ts_waitcnt vmcnt(0)"
                 : "=&v"(w) : "v"(glob) : "memory");
    if ((w.x >> 16) == want && (w.y >> 16) == want &&
        (w.z >> 16) == want && (w.w >> 16) == want) return w;
  }
}
__device__ inline void store4(u32* addr, u32x4 q){
  asm volatile("global_store_dwordx4 %0, %1, off sc0 sc1"
               :: "v"(addr), "v"(q) : "memory");
}
__device__ inline void store4_loc(u32* addr, u32x4 q){
  asm volatile("global_store_dwordx4 %0, %1, off sc0"
               :: "v"(addr), "v"(q) : "memory");
}

__device__ inline float wred_sum(float v){
#pragma unroll
  for (int m = 32; m >= 1; m >>= 1) v += __shfl_xor(v, m, 64);
  return v;
}
__device__ inline float bred_sum(float v, float* red, int tid){
  v = wred_sum(v);
  if ((tid & 63) == 0) red[tid >> 6] = v;
  __syncthreads();
  float r = red[0] + red[1] + red[2] + red[3];
  __syncthreads();
  return r;
}
__device__ inline float bred_max(float v, float* red, int tid){
#pragma unroll
  for (int m = 32; m >= 1; m >>= 1) v = fmaxf(v, __shfl_xor(v, m, 64));
  if ((tid & 63) == 0) red[tid >> 6] = v;
  __syncthreads();
  float r = fmaxf(fmaxf(red[0], red[1]), fmaxf(red[2], red[3]));
  __syncthreads();
  return r;
}

// 1024-dot, 4-elem chunks. Per-lane partial.
__device__ inline float dot1024(const u16* __restrict__ row, const float* h, int lane){
  float s = 0.f;
#pragma unroll
  for (int c = 0; c < 4; ++c){
    int e = 4 * lane + 256 * c;
    uint2 a = *(const uint2*)(row + e);
    float4 x = *(const float4*)(h + e);
    s = fmaf(bflo(a.x), x.x, s); s = fmaf(bfhi(a.x), x.y, s);
    s = fmaf(bflo(a.y), x.z, s); s = fmaf(bfhi(a.y), x.w, s);
  }
  return s;
}

// 4-row batched GEMV (rows r..r+3*rs), reduced.
__device__ inline float4 dot4(const u16* __restrict__ W, size_t r, size_t rs,
                              const float* h, int lane){
  const u16* p0 = W + (r         ) * 1024;
  const u16* p1 = W + (r + rs    ) * 1024;
  const u16* p2 = W + (r + 2 * rs) * 1024;
  const u16* p3 = W + (r + 3 * rs) * 1024;
  float s0 = 0, s1 = 0, s2 = 0, s3 = 0;
#pragma unroll
  for (int c = 0; c < 4; ++c){
    int e = 4 * lane + 256 * c;
    float4 x = *(const float4*)(h + e);
    uint2 a0 = *(const uint2*)(p0 + e);
    uint2 a1 = *(const uint2*)(p1 + e);
    uint2 a2 = *(const uint2*)(p2 + e);
    uint2 a3 = *(const uint2*)(p3 + e);
    s0 = fmaf(bflo(a0.x), x.x, s0); s0 = fmaf(bfhi(a0.x), x.y, s0);
    s0 = fmaf(bflo(a0.y), x.z, s0); s0 = fmaf(bfhi(a0.y), x.w, s0);
    s1 = fmaf(bflo(a1.x), x.x, s1); s1 = fmaf(bfhi(a1.x), x.y, s1);
    s1 = fmaf(bflo(a1.y), x.z, s1); s1 = fmaf(bfhi(a1.y), x.w, s1);
    s2 = fmaf(bflo(a2.x), x.x, s2); s2 = fmaf(bfhi(a2.x), x.y, s2);
    s2 = fmaf(bflo(a2.y), x.z, s2); s2 = fmaf(bfhi(a2.y), x.w, s2);
    s3 = fmaf(bflo(a3.x), x.x, s3); s3 = fmaf(bfhi(a3.x), x.y, s3);
    s3 = fmaf(bflo(a3.y), x.z, s3); s3 = fmaf(bfhi(a3.y), x.w, s3);
  }
  s0 = wred_sum(s0); s1 = wred_sum(s1); s2 = wred_sum(s2); s3 = wred_sum(s3);
  return make_float4(s0, s1, s2, s3);
}

// ---------------------------------------------------------------- fp32 -> bf16
__global__ void k_cvt(const float* __restrict__ s, u16* __restrict__ d, int n4){
  int i = blockIdx.x * 256 + threadIdx.x;
  int stride = gridDim.x * 256;
  const float4* s4 = (const float4*)s;
  for (; i < n4; i += stride){
    float4 v = s4[i];
    ushort4 o;
    o.x = f2bf(v.x); o.y = f2bf(v.y); o.z = f2bf(v.z); o.w = f2bf(v.w);
    ((ushort4*)d)[i] = o;
  }
}

// ---------------------------------------------------------------- img xp GEMM
__global__ __launch_bounds__(256, 1) void k_gemm_xp(
    const u16* __restrict__ A,
    const u16* __restrict__ B0, const u16* __restrict__ B1,
    const float* __restrict__ bias0, const float* __restrict__ bias1,
    float* __restrict__ C0, float* __restrict__ C1)
{
  const int K = 2048, N = 2048;
  const int bx = blockIdx.x, by = blockIdx.y, z = blockIdx.z;
  const u16* B = z ? B1 : B0;
  const float* bias = z ? bias1 : bias0;
  float* C = z ? C1 : C0;
  const int tid = threadIdx.x;
  const int lane = tid & 63, wv = tid >> 6;
  const int m0 = by * 128, n0 = bx * 128;
  const int wm = (wv >> 1) * 64, wn = (wv & 1) * 64;

  __shared__ __align__(16) u16 lA[128 * 32];
  __shared__ __align__(16) u16 lB[128 * 32];

  f32x4 acc[4][4];
#pragma unroll
  for (int i = 0; i < 4; ++i)
#pragma unroll
    for (int j = 0; j < 4; ++j) acc[i][j] = (f32x4){0.f, 0.f, 0.f, 0.f};

  const int lrow = tid >> 2;
  const int lcol = (tid & 3) * 8;
  const u16* aBase = A + (size_t)(m0 + lrow) * K + lcol;
  const u16* bBase = B + (size_t)(n0 + lrow) * K + lcol;

  for (int kk = 0; kk < K; kk += 32){
#pragma unroll
    for (int io = 0; io < 2; ++io){
      __builtin_amdgcn_global_load_lds(
        (const __attribute__((address_space(1))) void*)(aBase + (size_t)io * 64 * K + kk),
        (__attribute__((address_space(3))) void*)((char*)lA + wv * 1024 + io * 4096), 16, 0, 0);
      __builtin_amdgcn_global_load_lds(
        (const __attribute__((address_space(1))) void*)(bBase + (size_t)io * 64 * K + kk),
        (__attribute__((address_space(3))) void*)((char*)lB + wv * 1024 + io * 4096), 16, 0, 0);
    }
    asm volatile("s_waitcnt vmcnt(0)");
    __syncthreads();

    bf16x8 af[4], bfr[4];
#pragma unroll
    for (int i = 0; i < 4; ++i){
      af[i]  = *(const bf16x8*)&lA[(wm + i * 16 + (lane & 15)) * 32 + (lane >> 4) * 8];
      bfr[i] = *(const bf16x8*)&lB[(wn + i * 16 + (lane & 15)) * 32 + (lane >> 4) * 8];
    }
#pragma unroll
    for (int i = 0; i < 4; ++i)
#pragma unroll
      for (int j = 0; j < 4; ++j)
        acc[i][j] = __builtin_amdgcn_mfma_f32_16x16x32_bf16(af[i], bfr[j], acc[i][j], 0, 0, 0);
    __syncthreads();
  }

  const int rbase = (lane >> 4) * 4;
  const int ccol = lane & 15;
#pragma unroll
  for (int i = 0; i < 4; ++i)
#pragma unroll
    for (int j = 0; j < 4; ++j){
      int col = n0 + wn + j * 16 + ccol;
      float bv = bias[col];
#pragma unroll
      for (int r2 = 0; r2 < 4; ++r2){
        int row = m0 + wm + i * 16 + rbase + r2;
        C[(size_t)row * N + col] = acc[i][j][r2] + bv;
      }
    }
}

// ---------------------------------------------------------------- q xp
__global__ __launch_bounds__(256, 1) void k_qxp(
    const float* __restrict__ qf,
    const float* __restrict__ W0, const float* __restrict__ W1,
    const float* __restrict__ bb0, const float* __restrict__ bb1,
    float* __restrict__ o0, float* __restrict__ o1)
{
  const int bx = blockIdx.x;
  const int z = blockIdx.y;
  const float* W = z ? W1 : W0;
  const float* bb = z ? bb1 : bb0;
  float* o = z ? o1 : o0;
  const int tid = threadIdx.x;
  __shared__ float xs[32 * 301];
  __shared__ float Ws[64 * 301];
  for (int idx = tid; idx < 32 * 300; idx += 256){
    int m = idx / 300, k = idx - m * 300;
    xs[m * 301 + k] = qf[idx];
  }
  for (int idx = tid; idx < 64 * 300; idx += 256){
    int j = idx / 300, k = idx - j * 300;
    Ws[j * 301 + k] = W[(size_t)(bx * 64 + j) * 300 + k];
  }
  __syncthreads();
  for (int i = 0; i < 8; ++i){
    int idx = tid + i * 256;
    int nl = idx >> 5, m = idx & 31;
    float s = 0;
    for (int k = 0; k < 300; ++k) s = fmaf(xs[m * 301 + k], Ws[nl * 301 + k], s);
    o[(size_t)m * 2048 + bx * 64 + nl] = s + bb[bx * 64 + nl];
  }
}

// ---------------------------------------------------------------- LSTM scans
// VGPR weights.  Dual-mirror tagged exchange: publisher stores its wave's 4
// tagged words to a LOCAL mirror (sc0: same-XCD L2) then GLOBAL mirror
// (sc0 sc1).  Grid=256, dir=b&7 (<4 active), sub=b>>3: under the empirical
// blockIdx%8->XCD round-robin each direction's 32 blocks share one XCD, so
// local polls resolve in that L2 (~200cy vs ~900cy fabric).  Placement is a
// SPEED hint only — the global mirror guarantees progress anywhere.
// hl is parity double-buffered => single barrier per step is race-free:
// readers of hl[p] at step t finish before they reach barrier(t+1); writers
// touch hl[p] again only at step t+2, after leaving barrier(t+1).
__global__ __launch_bounds__(256, 1) void k_scan(
    const float* __restrict__ WhA, const float* __restrict__ WhB,
    const float* __restrict__ WhC, const float* __restrict__ WhD,
    const float* __restrict__ xpA, const float* __restrict__ xpB,
    const float* __restrict__ xpC, const float* __restrict__ xpD,
    float* __restrict__ emb, float* __restrict__ embT,
    float* __restrict__ qemb, float* __restrict__ qembT,
    u32* hcommL, u32* hcommG /* each [4][2][512] u32 = tag16<<16 | bf16 */)
{
  const int b = blockIdx.x;
  const int slot = b & 7;
  if (slot >= 4) return;
  const int dir = slot;
  const int sub = b >> 3;          // 0..31
  const int tid = threadIdx.x;
  const float* Wh = dir == 0 ? WhA : dir == 1 ? WhB : dir == 2 ? WhC : WhD;
  const float* xp = dir == 0 ? xpA : dir == 1 ? xpB : dir == 2 ? xpC : xpD;
  const int L = (dir < 2) ? 1024 : 32;
  const int rev = dir & 1;
  float* oe  = (dir < 2) ? emb  : qemb;
  float* oeT = (dir < 2) ? embT : qembT;
  const int colbase = rev ? 512 : 0;
  const int eTL = (dir < 2) ? 1024 : 32;
  const int hbase = sub * 16;
  const int lane = tid & 63, wv = tid >> 6;
  const int g = tid >> 4;        // h-element within block
  const int seg = tid & 15;      // k-chunk
  const bool pub = (seg == 0);

  __shared__ float hl[2][512];

  int grows[4];
#pragma unroll
  for (int gate = 0; gate < 4; ++gate) grows[gate] = gate * 512 + hbase + g;

  // one-time: weights -> registers (packed bf16 pairs)
  u32 wpk0[16], wpk1[16], wpk2[16], wpk3[16];
  {
    const float2* r0 = (const float2*)(Wh + (size_t)grows[0] * 512) + seg;
    const float2* r1 = (const float2*)(Wh + (size_t)grows[1] * 512) + seg;
    const float2* r2 = (const float2*)(Wh + (size_t)grows[2] * 512) + seg;
    const float2* r3 = (const float2*)(Wh + (size_t)grows[3] * 512) + seg;
#pragma unroll
    for (int i = 0; i < 16; ++i){
      float2 a0 = r0[16 * i], a1 = r1[16 * i], a2 = r2[16 * i], a3 = r3[16 * i];
      wpk0[i] = (u32)f2bf(a0.x) | ((u32)f2bf(a0.y) << 16);
      wpk1[i] = (u32)f2bf(a1.x) | ((u32)f2bf(a1.y) << 16);
      wpk2[i] = (u32)f2bf(a2.x) | ((u32)f2bf(a2.y) << 16);
      wpk3[i] = (u32)f2bf(a3.x) | ((u32)f2bf(a3.y) << 16);
    }
  }

  float creg = 0.f;
  float xpv[4] = {0.f, 0.f, 0.f, 0.f};
  if (pub){
    int t0 = rev ? (L - 1) : 0;
#pragma unroll
    for (int gate = 0; gate < 4; ++gate) xpv[gate] = xp[(size_t)t0 * 2048 + grows[gate]];
  }

  u32* hcl = hcommL + dir * 1024;  // [2][512]
  u32* hcg = hcommG + dir * 1024;

  for (int t = 0; t < L; ++t){
    const u32 want = (u32)t;      // h_t carries tag t (t=0 via memset)
    const int par = t & 1;
    if (tid < 128){
      int o = (par << 9) + 4 * tid;
      u32x4 w = poll4_dual(hcl + o, hcg + o, want);
      *(float4*)&hl[par][4 * tid] =
          make_float4(bflo(w.x), bflo(w.y), bflo(w.z), bflo(w.w));
    }
    __syncthreads();                    // hl[par](t) ready

    float2 hreg[16];
#pragma unroll
    for (int i = 0; i < 16; ++i) hreg[i] = *(const float2*)&hl[par][2 * (seg + 16 * i)];
    float s0 = 0, s1 = 0, s2 = 0, s3 = 0;
#pragma unroll
    for (int i = 0; i < 16; ++i){
      float hx = hreg[i].x, hy = hreg[i].y;
      s0 = fmaf(bflo(wpk0[i]), hx, s0); s0 = fmaf(bfhi(wpk0[i]), hy, s0);
      s1 = fmaf(bflo(wpk1[i]), hx, s1); s1 = fmaf(bfhi(wpk1[i]), hy, s1);
      s2 = fmaf(bflo(wpk2[i]), hx, s2); s2 = fmaf(bfhi(wpk2[i]), hy, s2);
      s3 = fmaf(bflo(wpk3[i]), hx, s3); s3 = fmaf(bfhi(wpk3[i]), hy, s3);
    }
#pragma unroll
    for (int m = 1; m < 16; m <<= 1){
      s0 += __shfl_xor(s0, m, 64); s1 += __shfl_xor(s1, m, 64);
      s2 += __shfl_xor(s2, m, 64); s3 += __shfl_xor(s3, m, 64);
    }
    u32 tg = 0;
    float hout = 0.f;
    if (pub){
      float gi = s0 + xpv[0], gf = s1 + xpv[1], gg = s2 + xpv[2], go = s3 + xpv[3];
      creg = sigm(gf) * creg + sigm(gi) * ftanh(gg);
      hout = sigm(go) * ftanh(creg);
      tg = ((u32)(t + 1) << 16) | (u32)f2bf(hout);
    }
    // gather 4 tagged words (lanes 0,16,32,48) -> lane 0 dual wide store
    u32 q0 = __shfl(tg, 0), q1 = __shfl(tg, 16), q2 = __shfl(tg, 32), q3 = __shfl(tg, 48);
    if (lane == 0){
      int o = (((t + 1) & 1) << 9) + hbase + 4 * wv;
      u32x4 q = {q0, q1, q2, q3};
      store4_loc(hcl + o, q);   // fast path (same-XCD L2)
      store4(hcg + o, q);       // correctness path (device scope)
    }
    if (pub){
      const int trow = rev ? (L - 1 - t) : t;
      int col = colbase + hbase + g;
      oe[(size_t)trow * 1024 + col] = hout;
      oeT[(size_t)col * eTL + trow] = hout;
      if (t + 1 < L){
        int tn = rev ? (L - 2 - t) : (t + 1);
#pragma unroll
        for (int gate = 0; gate < 4; ++gate) xpv[gate] = xp[(size_t)tn * 2048 + grows[gate]];
      }
    }
  }
}

// ---------------------------------------------------------------- decoder (64 blocks)
#define DG 64
__device__ inline void dbar(int* st, int b, int pc, int tid){
  __syncthreads();
  if (tid == 0) astorei_rel(&st[b], pc);
  if (tid < DG){
    while (aloadi(&st[tid]) < pc) {}
  }
  __syncthreads();
}

struct DecArgs {
  const float *emb, *embT, *qemb, *qembT;
  const float *Wimg_e, *bimg, *Wmod_img;
  const float *Wq_e, *bq, *Wmod_q;
  const float *Wmod, *bmod;
  const u16 *Wfus_bf; const float *bfus;
  const u16 *WfusI_bf, *WfusQ_bf;
  const u16 *Wid_bf, *Whd_bf; const float *b_dec;
  float *e_img, *m_img, *e_q, *m_q;
  float *a_img, *a_q, *ctx_img, *ctx_q;
  float *d_img, *d_q, *scal;
  u32 *tfs, *thdec;      // [1024] tagged u32 (tag16<<16 | bf16)
  float *hall;           // [T][1024] fp32 h_{t+1}
  int *st; int T;
};

__global__ __launch_bounds__(256, 1) void k_dec(DecArgs A)
{
  const int b = blockIdx.x, tid = threadIdx.x;
  const int lane = tid & 63, wv = tid >> 6;
  __shared__ __align__(16) float hl[1024];
  __shared__ __align__(16) float fsl[1024];
  __shared__ float red[4];
  __shared__ float gb[4][16];
  __shared__ float cdec[16];
  __shared__ float aql[32];
  int pc = 0;

  // ---- P0: e_img/m_img 16 rows/block (4/wave); e_q/m_q blocks 0..31
  {
#pragma unroll
    for (int rr = 0; rr < 4; ++rr){
      int l = b * 16 + wv * 4 + rr;
      const float* er = A.emb + (size_t)l * 1024;
      float se = 0, sm = 0;
#pragma unroll
      for (int i = 0; i < 16; ++i){
        int k = lane + (i << 6);
        float x = er[k];
        se = fmaf(x, A.Wimg_e[k], se);
        sm = fmaf(x, A.Wmod_img[k], sm);
      }
      se = wred_sum(se); sm = wred_sum(sm);
      if (lane == 0){ astoref(A.e_img + l, se + A.bimg[0]); astoref(A.m_img + l, sm); }
    }
    if (b < 32 && wv == 0){
      const float* qr = A.qemb + (size_t)b * 1024;
      float se2 = 0, sm2 = 0;
#pragma unroll
      for (int i = 0; i < 16; ++i){
        int k = lane + (i << 6);
        float x = qr[k];
        se2 = fmaf(x, A.Wq_e[k], se2);
        sm2 = fmaf(x, A.Wmod_q[k], sm2);
      }
      se2 = wred_sum(se2); sm2 = wred_sum(sm2);
      if (lane == 0){ astoref(A.e_q + b, se2 + A.bq[0]); astoref(A.m_q + b, sm2); }
    }
  }
  pc++; dbar(A.st, b, pc, tid);

  // ---- P1: block0 softmax (attention step-invariant)
  if (b == 0){
    for (int k = tid; k < 1024; k += 256){ fsl[k] = aloadf(A.e_img + k); hl[k] = aloadf(A.m_img + k); }
    __syncthreads();
    float lm = -3.4e38f;
    for (int k = tid; k < 1024; k += 256) lm = fmaxf(lm, fsl[k]);
    float M = bred_max(lm, red, tid);
    float ls = 0, lw = 0;
    for (int k = tid; k < 1024; k += 256){
      float e = expf(fsl[k] - M);
      fsl[k] = e; ls += e; lw += e * hl[k];
    }
    float S = bred_sum(ls, red, tid);
    float W = bred_sum(lw, red, tid);
    float inv = 1.f / S;
    for (int k = tid; k < 1024; k += 256) astoref(A.a_img + k, fsl[k] * inv);
    if (tid == 0) astoref(A.scal + 2, W * inv);
    if (tid < 64){
      float ev = (lane < 32) ? aloadf(A.e_q + lane) : -3.4e38f;
      float mv = (lane < 32) ? aloadf(A.m_q + lane) : 0.f;
      float M2 = ev;
#pragma unroll
      for (int m = 32; m >= 1; m >>= 1) M2 = fmaxf(M2, __shfl_xor(M2, m, 64));
      float e = (lane < 32) ? expf(ev - M2) : 0.f;
      float S2 = wred_sum(e);
      float W2 = wred_sum(e * mv);
      if (lane < 32) astoref(A.a_q + lane, e / S2);
      if (lane == 0) astoref(A.scal + 3, W2 / S2);
    }
  }
  pc++; dbar(A.st, b, pc, tid);

  // ---- P2: ctx (16 img cols + 16 q cols per block)
  {
    for (int k = tid; k < 1024; k += 256) hl[k] = aloadf(A.a_img + k);
    if (tid < 32) aql[tid] = aloadf(A.a_q + tid);
    __syncthreads();
#pragma unroll
    for (int cc = 0; cc < 4; ++cc){
      int c = b * 16 + wv * 4 + cc;
      const float* eT = A.embT + (size_t)c * 1024;
      float s = 0;
#pragma unroll
      for (int i = 0; i < 16; ++i){ int l = lane + (i << 6); s = fmaf(hl[l], eT[l], s); }
      s = wred_sum(s);
      if (lane == 0) astoref(A.ctx_img + c, s);
      const float* qT = A.qembT + (size_t)c * 32;
      float sq = (lane < 32) ? aql[lane] * qT[lane] : 0.f;
      sq = wred_sum(sq);
      if (lane == 0) astoref(A.ctx_q + c, sq);
    }
  }
  pc++; dbar(A.st, b, pc, tid);

  // ---- P3: d_img/d_q (4 rows per wave)
  for (int k = tid; k < 1024; k += 256){ hl[k] = aloadf(A.ctx_img + k); fsl[k] = aloadf(A.ctx_q + k); }
  __syncthreads();
  {
    int r = b * 16 + wv * 4;
    float4 si = dot4(A.WfusI_bf, (size_t)r, 1, hl, lane);
    float4 sq = dot4(A.WfusQ_bf, (size_t)r, 1, fsl, lane);
    if (lane == 0){
      astoref(A.d_img + r + 0, si.x); astoref(A.d_q + r + 0, sq.x);
      astoref(A.d_img + r + 1, si.y); astoref(A.d_q + r + 1, sq.y);
      astoref(A.d_img + r + 2, si.z); astoref(A.d_q + r + 2, sq.z);
      astoref(A.d_img + r + 3, si.w); astoref(A.d_q + r + 3, sq.w);
    }
  }
  pc++; dbar(A.st, b, pc, tid);

  // per-wave constants
  const int fr = b * 16 + wv * 4;
  float dimg_r[4], dq_r[4], bfus_r[4];
#pragma unroll
  for (int rr = 0; rr < 4; ++rr){
    dimg_r[rr] = aloadf(A.d_img + fr + rr);
    dq_r[rr]   = aloadf(A.d_q + fr + rr);
    bfus_r[rr] = A.bfus[fr + rr];
  }
  const float sc2 = aloadf(A.scal + 2), sc3 = aloadf(A.scal + 3);
  const float bmod0 = A.bmod[0];
  float wmod_r[4];
#pragma unroll
  for (int i = 0; i < 4; ++i) wmod_r[i] = A.Wmod[tid + (i << 8)];

  for (int k = tid; k < 1024; k += 256) hl[k] = 0.f;
  if (tid < 16) cdec[tid] = 0.f;
  __syncthreads();

  // ---- decode loop (logits deferred to k_logits)
  for (int t = 0; t < A.T; ++t){
    const u32 want = (u32)(t + 1);

    // mw computed redundantly by every block (identical fp sequence)
    float part = 0;
#pragma unroll
    for (int i = 0; i < 4; ++i) part = fmaf(wmod_r[i], hl[tid + (i << 8)], part);
    float tmp = bred_sum(part, red, tid) + bmod0;
    float wi_ = ftanh(tmp + sc2), wq_ = ftanh(tmp + sc3);
    float mx = fmaxf(wi_, wq_);
    float e0 = __expf(wi_ - mx), e1 = __expf(wq_ - mx);
    float inv01 = __builtin_amdgcn_rcpf(e0 + e1);
    float mw0 = e0 * inv01, mw1 = e1 * inv01;

    // fs rows (4 per wave) -> one wide tagged publish per wave
    {
      float4 sf = dot4(A.Wfus_bf, (size_t)fr, 1, hl, lane);
      if (lane == 0){
        float v0 = ftanh(sf.x + bfus_r[0] + mw0 * dimg_r[0] + mw1 * dq_r[0]);
        float v1 = ftanh(sf.y + bfus_r[1] + mw0 * dimg_r[1] + mw1 * dq_r[1]);
        float v2 = ftanh(sf.z + bfus_r[2] + mw0 * dimg_r[2] + mw1 * dq_r[2]);
        float v3 = ftanh(sf.w + bfus_r[3] + mw0 * dimg_r[3] + mw1 * dq_r[3]);
        u32x4 q = { (want << 16) | (u32)f2bf(v0), (want << 16) | (u32)f2bf(v1),
                    (want << 16) | (u32)f2bf(v2), (want << 16) | (u32)f2bf(v3) };
        store4(A.tfs + fr, q);
      }
    }

    // Whd gate half — depends only on hl: hoisted ABOVE the fs poll so its
    // ~32KB/wave of reads overlap the exchange latency.
    const size_t g0 = (size_t)wv * 1024 + b * 16;
    float4 sbq[4];
#pragma unroll
    for (int q4 = 0; q4 < 4; ++q4)
      sbq[q4] = dot4(A.Whd_bf, g0 + q4 * 4, 1, hl, lane);

    // poll fs -> fsl (one dwordx4 per thread covers 4 values)
    {
      u32x4 w = poll4(A.tfs + 4 * tid, want);
      *(float4*)&fsl[4 * tid] = make_float4(bflo(w.x), bflo(w.y), bflo(w.z), bflo(w.w));
    }
    __syncthreads();   // A

    // Wid gate half + combine
    {
#pragma unroll
      for (int q4 = 0; q4 < 4; ++q4){
        float4 sa = dot4(A.Wid_bf, g0 + q4 * 4, 1, fsl, lane);
        if (lane == 0){
          gb[wv][q4 * 4 + 0] = sa.x + sbq[q4].x + A.b_dec[g0 + q4 * 4 + 0];
          gb[wv][q4 * 4 + 1] = sa.y + sbq[q4].y + A.b_dec[g0 + q4 * 4 + 1];
          gb[wv][q4 * 4 + 2] = sa.z + sbq[q4].z + A.b_dec[g0 + q4 * 4 + 2];
          gb[wv][q4 * 4 + 3] = sa.w + sbq[q4].w + A.b_dec[g0 + q4 * 4 + 3];
        }
      }
    }
    __syncthreads();   // B
    u32 tg = 0;
    if (tid < 16){
      float gi = gb[0][tid], gf = gb[1][tid], gg = gb[2][tid], go = gb[3][tid];
      float c = sigm(gf) * cdec[tid] + sigm(gi) * ftanh(gg);
      cdec[tid] = c;
      float h = sigm(go) * ftanh(c);
      tg = (want << 16) | (u32)f2bf(h);
      A.hall[(size_t)t * 1024 + b * 16 + tid] = h;   // exact h for logits
    }
    if (wv == 0){
      u32 q0 = __shfl(tg, 4 * lane + 0), q1 = __shfl(tg, 4 * lane + 1);
      u32 q2 = __shfl(tg, 4 * lane + 2), q3 = __shfl(tg, 4 * lane + 3);
      if (lane < 4) store4(A.thdec + b * 16 + 4 * lane, (u32x4){q0, q1, q2, q3});
    }
    // poll h -> hl
    {
      u32x4 w = poll4(A.thdec + 4 * tid, want);
      *(float4*)&hl[4 * tid] = make_float4(bflo(w.x), bflo(w.y), bflo(w.z), bflo(w.w));
    }
    __syncthreads();   // C
  }
}

// ---------------------------------------------------------------- deferred logits
__global__ __launch_bounds__(256, 1) void k_logits(
    const u16* __restrict__ Wfin, const float* __restrict__ bfin,
    const float* __restrict__ hall, float* __restrict__ out, int T)
{
  __shared__ u32 hp[20 * 512];
  const int tid = threadIdx.x;
  const int lane = tid & 63, wv = tid >> 6;
  const int n2 = T * 512;
  for (int idx = tid; idx < n2; idx += 256){
    float2 v = ((const float2*)hall)[idx];
    hp[idx] = (u32)f2bf(v.x) | ((u32)f2bf(v.y) << 16);
  }
  __syncthreads();
  const int gwv = blockIdx.x * 4 + wv;
#pragma unroll
  for (int gset = 0; gset < 4; ++gset){
    int r0 = gwv * 16 + gset * 4;
    uint2 wreg[4][4];
#pragma unroll
    for (int rr = 0; rr < 4; ++rr){
      const uint2* wr = (const uint2*)(Wfin + (size_t)(r0 + rr) * 1024);
#pragma unroll
      for (int c = 0; c < 4; ++c) wreg[rr][c] = wr[lane + 64 * c];
    }
    for (int t = 0; t < T; ++t){
      const uint2* hp2 = (const uint2*)&hp[t * 512];
      float s0 = 0, s1 = 0, s2 = 0, s3 = 0;
#pragma unroll
      for (int c = 0; c < 4; ++c){
        uint2 hw = hp2[lane + 64 * c];
        float h0 = bflo(hw.x), h1 = bfhi(hw.x), h2 = bflo(hw.y), h3 = bfhi(hw.y);
        uint2 a;
        a = wreg[0][c];
        s0 = fmaf(bflo(a.x), h0, s0); s0 = fmaf(bfhi(a.x), h1, s0);
        s0 = fmaf(bflo(a.y), h2, s0); s0 = fmaf(bfhi(a.y), h3, s0);
        a = wreg[1][c];
        s1 = fmaf(bflo(a.x), h0, s1); s1 = fmaf(bfhi(a.x), h1, s1);
        s1 = fmaf(bflo(a.y), h2, s1); s1 = fmaf(bfhi(a.y), h3, s1);
        a = wreg[2][c];
        s2 = fmaf(bflo(a.x), h0, s2); s2 = fmaf(bfhi(a.x), h1, s2);
        s2 = fmaf(bflo(a.y), h2, s2); s2 = fmaf(bfhi(a.y), h3, s2);
        a = wreg[3][c];
        s3 = fmaf(bflo(a.x), h0, s3); s3 = fmaf(bfhi(a.x), h1, s3);
        s3 = fmaf(bflo(a.y), h2, s3); s3 = fmaf(bfhi(a.y), h3, s3);
      }
      s0 = wred_sum(s0); s1 = wred_sum(s1); s2 = wred_sum(s2); s3 = wred_sum(s3);
      if (lane == 0){
        float* orow = out + (size_t)t * 32000;
        orow[r0 + 0] = s0 + bfin[r0 + 0];
        orow[r0 + 1] = s1 + bfin[r0 + 1];
        orow[r0 + 2] = s2 + bfin[r0 + 2];
        orow[r0 + 3] = s3 + bfin[r0 + 3];
      }
    }
  }
}

// ---------------------------------------------------------------- host
extern "C" void kernel_launch(void* const* d_in, const int* in_sizes, int n_in,
                              void* d_out, int out_size, void* d_ws, size_t ws_size,
                              hipStream_t stream)
{
  const float* img_feats = (const float*)d_in[0];
  const float* q_feats   = (const float*)d_in[1];
  const float* Wi_imgf = (const float*)d_in[2];
  const float* Wh_imgf = (const float*)d_in[3];
  const float* b_imgf  = (const float*)d_in[4];
  const float* Wi_imgb = (const float*)d_in[5];
  const float* Wh_imgb = (const float*)d_in[6];
  const float* b_imgb  = (const float*)d_in[7];
  const float* Wi_qf = (const float*)d_in[8];
  const float* Wh_qf = (const float*)d_in[9];
  const float* b_qf  = (const float*)d_in[10];
  const float* Wi_qb = (const float*)d_in[11];
  const float* Wh_qb = (const float*)d_in[12];
  const float* b_qb  = (const float*)d_in[13];
  const float* Wimg_e = (const float*)d_in[15];
  const float* bimg   = (const float*)d_in[16];
  const float* Wq_e   = (const float*)d_in[18];
  const float* bq     = (const float*)d_in[19];
  const float* Wmod   = (const float*)d_in[20];
  const float* bmod   = (const float*)d_in[21];
  const float* Wmod_img = (const float*)d_in[22];
  const float* Wmod_q   = (const float*)d_in[23];
  const float* Wfus_img = (const float*)d_in[24];
  const float* Wfus_q   = (const float*)d_in[25];
  const float* Wfus     = (const float*)d_in[26];
  const float* bfus     = (const float*)d_in[27];
  const float* Wi_dec = (const float*)d_in[28];
  const float* Wh_dec = (const float*)d_in[29];
  const float* b_dec  = (const float*)d_in[30];
  const float* Wfin = (const float*)d_in[31];
  const float* bfin = (const float*)d_in[32];
  const int T = out_size / 32000;

  char* ws = (char*)d_ws;
  size_t off = 0;
  auto alloc = [&](size_t bytes){ size_t o = off; off += (bytes + 255) & ~(size_t)255; return o; };
  const size_t oA    = alloc(1024ull * 2048 * 2);
  const size_t oWiF  = alloc(2048ull * 2048 * 2);
  const size_t oWiB  = alloc(2048ull * 2048 * 2);
  const size_t oWfin = alloc(32000ull * 1024 * 2);
  const size_t oWfu  = alloc(1024ull * 1024 * 2);
  const size_t oWfI  = alloc(1024ull * 1024 * 2);
  const size_t oWfQ  = alloc(1024ull * 1024 * 2);
  const size_t oWid  = alloc(4096ull * 1024 * 2);
  const size_t oWhd  = alloc(4096ull * 1024 * 2);
  const size_t oxpF  = alloc(1024ull * 2048 * 4);
  const size_t oxpB  = alloc(1024ull * 2048 * 4);
  const size_t oxpQF = alloc(32ull * 2048 * 4);
  const size_t oxpQB = alloc(32ull * 2048 * 4);
  const size_t oemb  = alloc(1024ull * 1024 * 4);
  const size_t oembT = alloc(1024ull * 1024 * 4);
  const size_t oqemb = alloc(32ull * 1024 * 4);
  const size_t oqembT= alloc(1024ull * 32 * 4);
  const size_t ohall = alloc(20ull * 1024 * 4);
  const size_t oeimg = alloc(1024 * 4);
  const size_t omimg = alloc(1024 * 4);
  const size_t oeq   = alloc(32 * 4);
  const size_t omq   = alloc(32 * 4);
  const size_t oaimg = alloc(1024 * 4);
  const size_t oaq   = alloc(32 * 4);
  const size_t octxi = alloc(1024 * 4);
  const size_t octxq = alloc(1024 * 4);
  const size_t odimg = alloc(1024 * 4);
  const size_t odq   = alloc(1024 * 4);
  const size_t oCTRL = off;
  const size_t ohcommL = alloc(4ull * 2 * 512 * 4);
  const size_t ohcommG = alloc(4ull * 2 * 512 * 4);
  const size_t otfs   = alloc(1024 * 4);
  const size_t othdec = alloc(1024 * 4);
  const size_t odst   = alloc(64 * 4);
  const size_t oscal  = alloc(64 * 4);
  const size_t ctrlBytes = off - oCTRL;
  (void)ws_size; (void)n_in; (void)in_sizes;

  hipMemsetAsync(ws + oCTRL, 0, ctrlBytes, stream);

  auto cvt = [&](const float* s, size_t o, long n){
    int n4 = (int)(n >> 2);
    int g = (n4 + 255) / 256; if (g > 2048) g = 2048;
    k_cvt<<<dim3(g), dim3(256), 0, stream>>>(s, (u16*)(ws + o), n4);
  };
  cvt(img_feats, oA, 1024L * 2048);
  cvt(Wi_imgf, oWiF, 2048L * 2048);
  cvt(Wi_imgb, oWiB, 2048L * 2048);
  cvt(Wfin, oWfin, 32000L * 1024);
  cvt(Wfus, oWfu, 1024L * 1024);
  cvt(Wfus_img, oWfI, 1024L * 1024);
  cvt(Wfus_q, oWfQ, 1024L * 1024);
  cvt(Wi_dec, oWid, 4096L * 1024);
  cvt(Wh_dec, oWhd, 4096L * 1024);

  k_gemm_xp<<<dim3(16, 8, 2), dim3(256), 0, stream>>>(
      (const u16*)(ws + oA), (const u16*)(ws + oWiF), (const u16*)(ws + oWiB),
      b_imgf, b_imgb, (float*)(ws + oxpF), (float*)(ws + oxpB));

  k_qxp<<<dim3(32, 2), dim3(256), 0, stream>>>(
      q_feats, Wi_qf, Wi_qb, b_qf, b_qb,
      (float*)(ws + oxpQF), (float*)(ws + oxpQB));

  k_scan<<<dim3(256), dim3(256), 0, stream>>>(
      Wh_imgf, Wh_imgb, Wh_qf, Wh_qb,
      (const float*)(ws + oxpF), (const float*)(ws + oxpB),
      (const float*)(ws + oxpQF), (const float*)(ws + oxpQB),
      (float*)(ws + oemb), (float*)(ws + oembT),
      (float*)(ws + oqemb), (float*)(ws + oqembT),
      (u32*)(ws + ohcommL), (u32*)(ws + ohcommG));

  DecArgs DA;
  DA.emb = (const float*)(ws + oemb); DA.embT = (const float*)(ws + oembT);
  DA.qemb = (const float*)(ws + oqemb); DA.qembT = (const float*)(ws + oqembT);
  DA.Wimg_e = Wimg_e; DA.bimg = bimg; DA.Wmod_img = Wmod_img;
  DA.Wq_e = Wq_e; DA.bq = bq; DA.Wmod_q = Wmod_q;
  DA.Wmod = Wmod; DA.bmod = bmod;
  DA.Wfus_bf = (const u16*)(ws + oWfu); DA.bfus = bfus;
  DA.WfusI_bf = (const u16*)(ws + oWfI); DA.WfusQ_bf = (const u16*)(ws + oWfQ);
  DA.Wid_bf = (const u16*)(ws + oWid); DA.Whd_bf = (const u16*)(ws + oWhd); DA.b_dec = b_dec;
  DA.e_img = (float*)(ws + oeimg); DA.m_img = (float*)(ws + omimg);
  DA.e_q = (float*)(ws + oeq); DA.m_q = (float*)(ws + omq);
  DA.a_img = (float*)(ws + oaimg); DA.a_q = (float*)(ws + oaq);
  DA.ctx_img = (float*)(ws + octxi); DA.ctx_q = (float*)(ws + octxq);
  DA.d_img = (float*)(ws + odimg); DA.d_q = (float*)(ws + odq);
  DA.scal = (float*)(ws + oscal);
  DA.tfs = (u32*)(ws + otfs); DA.thdec = (u32*)(ws + othdec);
  DA.hall = (float*)(ws + ohall);
  DA.st = (int*)(ws + odst); DA.T = T;

  k_dec<<<dim3(DG), dim3(256), 0, stream>>>(DA);

  k_logits<<<dim3(500), dim3(256), 0, stream>>>(
      (const u16*)(ws + oWfin), bfin, (const float*)(ws + ohall),
      (float*)d_out, T);
}